// Round 12
// baseline (267.639 us; speedup 1.0000x reference)
//
#include <hip/hip_runtime.h>
#include <hip/hip_bf16.h>

// Pipeline (no global atomics — they write through to HBM per-op on MI355X;
// rounds 3/4). Build kernels need >=256 blocks and multi-block scans
// (rounds 5/7). Round 12: layer-2 dual-GEMM fused into the layer-1 gather
// (k_gather_gemm): per-node in-wave matvec vs LDS-staged transposed W
// (stride 65), t double-buffered; grid-stride 2048 blocks so W staging is
// per-resident-block, not per-node-group. Gather FETCH (~41MB) is at the
// 8-XCD cold-miss floor (round 10/11) — wins come from deleting passes.

#define NCHUNK 32     // edge chunks
#define NRANGE_H 4    // hist node ranges (range = 12500)
#define HIST_H 12544
#define NRANGE_B 8    // bin2 node ranges (range = 6250; needs 2 LDS arrays)
#define HIST_B 6272
#define FUSE_BLOCKS 2048

// ---------- partial histograms: a=0 deg over row, a=1 indeg over col ----------
__global__ __launch_bounds__(1024) void k_hist(const int* __restrict__ ei,
                                               int* __restrict__ partial,
                                               int N, int E, int range) {
  __shared__ int hist[HIST_H];
  int c = blockIdx.x % NCHUNK;
  int r = (blockIdx.x / NCHUNK) % NRANGE_H;
  int a = blockIdx.x / (NCHUNK * NRANGE_H);
  const int* ids = ei + (size_t)a * E;
  int lo = r * range;
  int hi = min(N, lo + range);
  int len = hi - lo;
  for (int i = threadIdx.x; i < len; i += 1024) hist[i] = 0;
  __syncthreads();
  int e0 = (int)((long long)E * c / NCHUNK);
  int e1 = (int)((long long)E * (c + 1) / NCHUNK);
  for (int e = e0 + threadIdx.x; e < e1; e += 1024) {
    int id = ids[e];
    if (id >= lo && id < hi) atomicAdd(&hist[id - lo], 1);  // LDS atomic
  }
  __syncthreads();
  int* dst = partial + ((size_t)a * NCHUNK + c) * N + lo;
  for (int i = threadIdx.x; i < len; i += 1024) dst[i] = hist[i];
}

// ---------- fused: reduce partials -> dinv/indeg, then in-block exscan ----------
__global__ __launch_bounds__(1024) void k_dinv_scan(const int* __restrict__ partial,
                                                    float* __restrict__ dinv,
                                                    int* __restrict__ indeg,
                                                    int* __restrict__ ptr,
                                                    int* __restrict__ bsum, int N) {
  __shared__ int s[1024];
  int g = blockIdx.x * 1024 + threadIdx.x;
  int deg = 0, ind = 0;
  if (g < N) {
#pragma unroll
    for (int c = 0; c < NCHUNK; ++c) {
      deg += partial[(size_t)c * N + g];
      ind += partial[((size_t)NCHUNK + c) * N + g];
    }
    dinv[g] = (deg > 0) ? (1.0f / sqrtf((float)deg)) : 0.0f;
    indeg[g] = ind;
  }
  s[threadIdx.x] = ind;
  __syncthreads();
  for (int off = 1; off < 1024; off <<= 1) {
    int tv = (threadIdx.x >= off) ? s[threadIdx.x - off] : 0;
    __syncthreads();
    s[threadIdx.x] += tv;
    __syncthreads();
  }
  if (g < N) ptr[g] = s[threadIdx.x] - ind;  // exclusive within block
  if (threadIdx.x == 1023) bsum[blockIdx.x] = s[1023];
}

// ---------- fused: scan bsum (in LDS) + finalize ptr + emit bases ----------
__global__ __launch_bounds__(256) void k_base(const int* __restrict__ partial,
                                              const int* __restrict__ bsum,
                                              int* __restrict__ ptr,
                                              int* __restrict__ base, int N, int nb) {
  __shared__ int pbs[64];
  if (threadIdx.x == 0) {
    int acc = 0;
    for (int i = 0; i < nb; ++i) { pbs[i] = acc; acc += bsum[i]; }
  }
  __syncthreads();
  int n = blockIdx.x * 256 + threadIdx.x;
  if (n >= N) return;
  int run = ptr[n] + pbs[n >> 10];
  ptr[n] = run;                      // final global exclusive scan
#pragma unroll
  for (int c = 0; c < NCHUNK; ++c) {
    base[(size_t)c * N + n] = run;
    run += partial[((size_t)NCHUNK + c) * N + n];
  }
}

// ---------- counting-sort binning (LDS atomics; base slice preloaded) ----------
__global__ __launch_bounds__(1024) void k_bin2(const int* __restrict__ ei,
                                               const int* __restrict__ base,
                                               int* __restrict__ csr_row,
                                               int N, int E, int range) {
  __shared__ int cnt[HIST_B];
  __shared__ int base_s[HIST_B];
  int c = blockIdx.x % NCHUNK;
  int r = blockIdx.x / NCHUNK;
  const int* row = ei;
  const int* col = ei + E;
  int lo = r * range;
  int hi = min(N, lo + range);
  int len = hi - lo;
  const int* bsrc = base + (size_t)c * N + lo;
  for (int i = threadIdx.x; i < len; i += 1024) {
    cnt[i] = 0;
    base_s[i] = bsrc[i];
  }
  __syncthreads();
  int e0 = (int)((long long)E * c / NCHUNK);
  int e1 = (int)((long long)E * (c + 1) / NCHUNK);
  for (int e = e0 + threadIdx.x; e < e1; e += 1024) {
    int cl = col[e];
    int rw = row[e];
    if (cl >= lo && cl < hi) {
      int off = atomicAdd(&cnt[cl - lo], 1);   // LDS atomic
      csr_row[base_s[cl - lo] + off] = rw;     // plain store (L2-absorbed)
    }
  }
}

// ---------- dual GEMM (layer 1): t = (x@Wn)*dinv[row] (bf16), agg = x@Wi + bias ----------
__global__ __launch_bounds__(256) void k_dual_gemm(
    const float* __restrict__ h,
    const float* __restrict__ Wn,
    const float* __restrict__ Wi,
    const float* __restrict__ bias,
    const float* __restrict__ dinv,
    __hip_bfloat16* __restrict__ t, float* __restrict__ agg, int N) {
  __shared__ float Wn_s[64 * 64];
  __shared__ float Wi_s[64 * 64];
  __shared__ float b_s[64];
  __shared__ float h_s[32 * 68];   // 32 rows, stride 68 (pad kills store conflicts)

  const int tid = threadIdx.x;
  {
    const float4* Wn4 = (const float4*)Wn;
    const float4* Wi4 = (const float4*)Wi;
    for (int i = tid; i < 1024; i += 256) {
      ((float4*)Wn_s)[i] = Wn4[i];
      ((float4*)Wi_s)[i] = Wi4[i];
    }
  }
  if (tid < 64) b_s[tid] = bias[tid];

  const int j = tid & 63;      // output column
  const int rg = tid >> 6;     // row group 0..3 -> rows rg*8..rg*8+7
  const int r0 = blockIdx.x * 64;

  for (int g = 0; g < 2; ++g) {
    __syncthreads();
    for (int v = tid; v < 512; v += 256) {
      int rr = v >> 4;
      int c4 = v & 15;
      int rload = r0 + g * 32 + rr;
      float4 val = make_float4(0.f, 0.f, 0.f, 0.f);
      if (rload < N) val = *(const float4*)&h[(size_t)rload * 64 + c4 * 4];
      *(float4*)&h_s[rr * 68 + c4 * 4] = val;
    }
    __syncthreads();

    float acc_t[8] = {0.f, 0.f, 0.f, 0.f, 0.f, 0.f, 0.f, 0.f};
    float acc_a[8] = {0.f, 0.f, 0.f, 0.f, 0.f, 0.f, 0.f, 0.f};
    for (int k4 = 0; k4 < 16; ++k4) {
      float4 hv[8];
#pragma unroll
      for (int r = 0; r < 8; ++r)
        hv[r] = *(const float4*)&h_s[(rg * 8 + r) * 68 + k4 * 4];
#pragma unroll
      for (int kk = 0; kk < 4; ++kk) {
        int k = k4 * 4 + kk;
        float wn = Wn_s[k * 64 + j];
        float wi = Wi_s[k * 64 + j];
#pragma unroll
        for (int r = 0; r < 8; ++r) {
          float hk = ((const float*)&hv[r])[kk];
          acc_t[r] = fmaf(hk, wn, acc_t[r]);
          acc_a[r] = fmaf(hk, wi, acc_a[r]);
        }
      }
    }
#pragma unroll
    for (int r = 0; r < 8; ++r) {
      int rr = r0 + g * 32 + rg * 8 + r;
      if (rr < N) {
        t[(size_t)rr * 64 + j] = __float2bfloat16(acc_t[r] * dinv[rr]);
        agg[(size_t)rr * 64 + j] = acc_a[r] + b_s[j];
      }
    }
  }
}

// ---------- eighth-wave CSR gather core ----------
// lane = o*8 + fl; t pre-scaled by dinv[src]; pure-add inner loop.
// After 3 shfl steps, acc[0..7] (features 8fl..8fl+7) replicated across o.
__device__ __forceinline__ void gather_core(
    const int* __restrict__ csr_row, const __hip_bfloat16* __restrict__ t,
    int i0, int end, int o, int fl, float* acc) {
#pragma unroll
  for (int k = 0; k < 8; ++k) acc[k] = 0.f;
  int i = i0 + o;
  for (; i + 8 < end; i += 16) {
    int ra = csr_row[i];
    int rb = csr_row[i + 8];
    uint4 ua = *(const uint4*)&t[(size_t)ra * 64 + 8 * fl];
    uint4 ub = *(const uint4*)&t[(size_t)rb * 64 + 8 * fl];
    float va[8], vb[8];
    ((unsigned*)va)[0] = ua.x << 16; ((unsigned*)va)[1] = ua.x & 0xFFFF0000u;
    ((unsigned*)va)[2] = ua.y << 16; ((unsigned*)va)[3] = ua.y & 0xFFFF0000u;
    ((unsigned*)va)[4] = ua.z << 16; ((unsigned*)va)[5] = ua.z & 0xFFFF0000u;
    ((unsigned*)va)[6] = ua.w << 16; ((unsigned*)va)[7] = ua.w & 0xFFFF0000u;
    ((unsigned*)vb)[0] = ub.x << 16; ((unsigned*)vb)[1] = ub.x & 0xFFFF0000u;
    ((unsigned*)vb)[2] = ub.y << 16; ((unsigned*)vb)[3] = ub.y & 0xFFFF0000u;
    ((unsigned*)vb)[4] = ub.z << 16; ((unsigned*)vb)[5] = ub.z & 0xFFFF0000u;
    ((unsigned*)vb)[6] = ub.w << 16; ((unsigned*)vb)[7] = ub.w & 0xFFFF0000u;
#pragma unroll
    for (int k = 0; k < 8; ++k) acc[k] += va[k] + vb[k];
  }
  for (; i < end; i += 8) {
    int ra = csr_row[i];
    uint4 ua = *(const uint4*)&t[(size_t)ra * 64 + 8 * fl];
    float va[8];
    ((unsigned*)va)[0] = ua.x << 16; ((unsigned*)va)[1] = ua.x & 0xFFFF0000u;
    ((unsigned*)va)[2] = ua.y << 16; ((unsigned*)va)[3] = ua.y & 0xFFFF0000u;
    ((unsigned*)va)[4] = ua.z << 16; ((unsigned*)va)[5] = ua.z & 0xFFFF0000u;
    ((unsigned*)va)[6] = ua.w << 16; ((unsigned*)va)[7] = ua.w & 0xFFFF0000u;
#pragma unroll
    for (int k = 0; k < 8; ++k) acc[k] += va[k];
  }
#pragma unroll
  for (int s = 8; s <= 32; s <<= 1) {
#pragma unroll
    for (int k = 0; k < 8; ++k) acc[k] += __shfl_xor(acc[k], s);
  }
}

// ---------- FUSED layer-1 gather + layer-2 dual GEMM ----------
// Per node: h2 = relu(agg1[n] + dn*gather(t1)); t2[n] = (h2@Wn2)*dn;
// agg[n] = h2@Wi2 + b2 (in place). W staged transposed (stride 65) for
// conflict-free b128 column reads. Grid-stride: W staged once per block.
__global__ __launch_bounds__(256) void k_gather_gemm(
    const int* __restrict__ csr_row, const int* __restrict__ ptr,
    const int* __restrict__ indeg, const float* __restrict__ dinv,
    const __hip_bfloat16* __restrict__ t1, float* __restrict__ agg,
    const float* __restrict__ Wn, const float* __restrict__ Wi,
    const float* __restrict__ bias,
    __hip_bfloat16* __restrict__ t2, int N) {
  __shared__ float Wn_t[64 * 65];
  __shared__ float Wi_t[64 * 65];
  __shared__ float b_s[64];
  __shared__ float rowbuf[4][64];

  const int tid = threadIdx.x;
  for (int i = tid; i < 4096; i += 256) {
    int k = i >> 6, j = i & 63;
    Wn_t[j * 65 + k] = Wn[i];
    Wi_t[j * 65 + k] = Wi[i];
  }
  if (tid < 64) b_s[tid] = bias[tid];
  __syncthreads();   // once; no barriers in the node loop

  const int w = tid >> 6;
  const int lane = tid & 63;
  const int o = lane >> 3;
  const int fl = lane & 7;

  for (int n = blockIdx.x * 4 + w; n < N; n += FUSE_BLOCKS * 4) {
    int i0 = ptr[n];
    int end = i0 + indeg[n];
    float dn = dinv[n];

    float acc[8];
    gather_core(csr_row, t1, i0, end, o, fl, acc);

    if (o == 0) {   // 8 lanes cover the full 64-feature row
      float4 a0 = *(const float4*)&agg[(size_t)n * 64 + 8 * fl];
      float4 a1 = *(const float4*)&agg[(size_t)n * 64 + 8 * fl + 4];
      rowbuf[w][8 * fl + 0] = fmaxf(a0.x + dn * acc[0], 0.f);
      rowbuf[w][8 * fl + 1] = fmaxf(a0.y + dn * acc[1], 0.f);
      rowbuf[w][8 * fl + 2] = fmaxf(a0.z + dn * acc[2], 0.f);
      rowbuf[w][8 * fl + 3] = fmaxf(a0.w + dn * acc[3], 0.f);
      rowbuf[w][8 * fl + 4] = fmaxf(a1.x + dn * acc[4], 0.f);
      rowbuf[w][8 * fl + 5] = fmaxf(a1.y + dn * acc[5], 0.f);
      rowbuf[w][8 * fl + 6] = fmaxf(a1.z + dn * acc[6], 0.f);
      rowbuf[w][8 * fl + 7] = fmaxf(a1.w + dn * acc[7], 0.f);
    }
    // same-wave LDS RAW (write then read, in-order DS pipe) — no barrier.
    float accT = 0.f, accA = 0.f;
#pragma unroll
    for (int k4 = 0; k4 < 16; ++k4) {
      float4 hr = *(const float4*)&rowbuf[w][k4 * 4];
      float4 wn = *(const float4*)&Wn_t[lane * 65 + k4 * 4];
      float4 wi = *(const float4*)&Wi_t[lane * 65 + k4 * 4];
      accT = fmaf(hr.x, wn.x, accT); accT = fmaf(hr.y, wn.y, accT);
      accT = fmaf(hr.z, wn.z, accT); accT = fmaf(hr.w, wn.w, accT);
      accA = fmaf(hr.x, wi.x, accA); accA = fmaf(hr.y, wi.y, accA);
      accA = fmaf(hr.z, wi.z, accA); accA = fmaf(hr.w, wi.w, accA);
    }
    t2[(size_t)n * 64 + lane] = __float2bfloat16(accT * dn);
    agg[(size_t)n * 64 + lane] = accA + b_s[lane];
  }
}

// ---------- FUSED layer-2 gather + output GEMM (grid-stride) ----------
__global__ __launch_bounds__(256) void k_gather_out(
    const int* __restrict__ csr_row, const int* __restrict__ ptr,
    const int* __restrict__ indeg, const float* __restrict__ dinv,
    const __hip_bfloat16* __restrict__ t, const float* __restrict__ agg,
    const float* __restrict__ Wo,   // [64,32]
    const float* __restrict__ bo,   // [32]
    float* __restrict__ out, int N) {
  __shared__ float Wo_t[32 * 65];
  __shared__ float bo_s[32];
  __shared__ float rowbuf[4][64];

  const int tid = threadIdx.x;
  for (int i = tid; i < 2048; i += 256) {
    int k = i >> 5, j = i & 31;
    Wo_t[j * 65 + k] = Wo[i];
  }
  if (tid < 32) bo_s[tid] = bo[tid];
  __syncthreads();   // once; no barriers in the node loop

  const int w = tid >> 6;
  const int lane = tid & 63;
  const int o = lane >> 3;
  const int fl = lane & 7;
  const int half = lane >> 5;
  const int j = lane & 31;

  for (int n = blockIdx.x * 4 + w; n < N; n += FUSE_BLOCKS * 4) {
    int i0 = ptr[n];
    int end = i0 + indeg[n];
    float dn = dinv[n];

    float acc[8];
    gather_core(csr_row, t, i0, end, o, fl, acc);

    if (o == 0) {
      float4 a0 = *(const float4*)&agg[(size_t)n * 64 + 8 * fl];
      float4 a1 = *(const float4*)&agg[(size_t)n * 64 + 8 * fl + 4];
      rowbuf[w][8 * fl + 0] = fmaxf(a0.x + dn * acc[0], 0.f);
      rowbuf[w][8 * fl + 1] = fmaxf(a0.y + dn * acc[1], 0.f);
      rowbuf[w][8 * fl + 2] = fmaxf(a0.z + dn * acc[2], 0.f);
      rowbuf[w][8 * fl + 3] = fmaxf(a0.w + dn * acc[3], 0.f);
      rowbuf[w][8 * fl + 4] = fmaxf(a1.x + dn * acc[4], 0.f);
      rowbuf[w][8 * fl + 5] = fmaxf(a1.y + dn * acc[5], 0.f);
      rowbuf[w][8 * fl + 6] = fmaxf(a1.z + dn * acc[6], 0.f);
      rowbuf[w][8 * fl + 7] = fmaxf(a1.w + dn * acc[7], 0.f);
    }
    // same-wave LDS RAW — no barrier.
    float ov = 0.f;
#pragma unroll
    for (int k4 = half * 8; k4 < half * 8 + 8; ++k4) {
      float4 hr = *(const float4*)&rowbuf[w][k4 * 4];
      float4 wv = *(const float4*)&Wo_t[j * 65 + k4 * 4];
      ov = fmaf(hr.x, wv.x, ov); ov = fmaf(hr.y, wv.y, ov);
      ov = fmaf(hr.z, wv.z, ov); ov = fmaf(hr.w, wv.w, ov);
    }
    ov += __shfl_xor(ov, 32);
    if (half == 0) out[(size_t)n * 32 + j] = ov + bo_s[j];
  }
}

extern "C" void kernel_launch(void* const* d_in, const int* in_sizes, int n_in,
                              void* d_out, int out_size, void* d_ws, size_t ws_size,
                              hipStream_t stream) {
  const float* x = (const float*)d_in[0];
  const int* ei = (const int*)d_in[1];
  const float* W_in1 = (const float*)d_in[2];
  const float* W_neigh1 = (const float*)d_in[3];
  const float* bias1 = (const float*)d_in[4];
  const float* W_in2 = (const float*)d_in[5];
  const float* W_neigh2 = (const float*)d_in[6];
  const float* bias2 = (const float*)d_in[7];
  const float* W_out = (const float*)d_in[8];
  const float* b_out = (const float*)d_in[9];
  float* out = (float*)d_out;

  const int N = in_sizes[0] / 64;
  const int E = in_sizes[1] / 2;

  char* ws = (char*)d_ws;
  size_t off = 0;
  auto alloc = [&](size_t bytes) -> void* {
    void* p = ws + off;
    off += (bytes + 255) & ~(size_t)255;
    return p;
  };
  float* dinv = (float*)alloc((size_t)N * 4);
  int* indeg = (int*)alloc((size_t)N * 4);
  int* ptr = (int*)alloc((size_t)N * 4);
  int* bsum = (int*)alloc(256);
  int* csr_row = (int*)alloc((size_t)E * 4);
  int* partial = (int*)alloc((size_t)2 * NCHUNK * N * 4);
  int* base = (int*)alloc((size_t)NCHUNK * N * 4);
  __hip_bfloat16* t1 = (__hip_bfloat16*)alloc((size_t)N * 64 * 2);
  __hip_bfloat16* t2 = (__hip_bfloat16*)alloc((size_t)N * 64 * 2);
  float* agg = (float*)alloc((size_t)N * 64 * 4);
  (void)ws_size;

  int range_h = (N + NRANGE_H - 1) / NRANGE_H;  // 12500 <= HIST_H
  int range_b = (N + NRANGE_B - 1) / NRANGE_B;  // 6250  <= HIST_B
  int gN = (N + 255) / 256;
  int gRows = (N + 63) / 64;
  int nb = (N + 1023) / 1024;

  k_hist<<<2 * NRANGE_H * NCHUNK, 1024, 0, stream>>>(ei, partial, N, E, range_h);
  k_dinv_scan<<<nb, 1024, 0, stream>>>(partial, dinv, indeg, ptr, bsum, N);
  k_base<<<gN, 256, 0, stream>>>(partial, bsum, ptr, base, N, nb);
  k_bin2<<<NRANGE_B * NCHUNK, 1024, 0, stream>>>(ei, base, csr_row, N, E, range_b);

  // layer 1 GEMM: t1 = (x@Wn1)*dinv, agg = x@Wi1 + b1
  k_dual_gemm<<<gRows, 256, 0, stream>>>(x, W_neigh1, W_in1, bias1, dinv, t1, agg, N);

  // fused: layer-1 gather + layer-2 dual GEMM (agg in place, t2 fresh)
  k_gather_gemm<<<FUSE_BLOCKS, 256, 0, stream>>>(csr_row, ptr, indeg, dinv, t1, agg,
                                                 W_neigh2, W_in2, bias2, t2, N);

  // fused: layer-2 gather + output GEMM
  k_gather_out<<<FUSE_BLOCKS, 256, 0, stream>>>(csr_row, ptr, indeg, dinv, t2, agg,
                                                W_out, b_out, out, N);
}

// Round 13
// 234.366 us; speedup vs baseline: 1.1420x; 1.1420x over previous
//
#include <hip/hip_runtime.h>
#include <hip/hip_bf16.h>

// Pipeline (no global atomics — they write through to HBM per-op on MI355X;
// rounds 3/4). Build kernels need >=256 blocks and multi-block scans
// (rounds 5/7). Round-12 lesson: do NOT fuse matvecs into the latency-bound
// gathers (occupancy 65%->19%, 2x regression) and do NOT grid-stride the
// gather_out (per-block W staging at 12500 blocks is the proven structure).
// Round 13 = round-10 structure + dinv-prescale of t (gather inner loop is
// pure adds; dinv[n] applied once after the reduction).

#define NCHUNK 32     // edge chunks
#define NRANGE_H 4    // hist node ranges (range = 12500)
#define HIST_H 12544
#define NRANGE_B 8    // bin2 node ranges (range = 6250; needs 2 LDS arrays)
#define HIST_B 6272

// ---------- partial histograms: a=0 deg over row, a=1 indeg over col ----------
__global__ __launch_bounds__(1024) void k_hist(const int* __restrict__ ei,
                                               int* __restrict__ partial,
                                               int N, int E, int range) {
  __shared__ int hist[HIST_H];
  int c = blockIdx.x % NCHUNK;
  int r = (blockIdx.x / NCHUNK) % NRANGE_H;
  int a = blockIdx.x / (NCHUNK * NRANGE_H);
  const int* ids = ei + (size_t)a * E;
  int lo = r * range;
  int hi = min(N, lo + range);
  int len = hi - lo;
  for (int i = threadIdx.x; i < len; i += 1024) hist[i] = 0;
  __syncthreads();
  int e0 = (int)((long long)E * c / NCHUNK);
  int e1 = (int)((long long)E * (c + 1) / NCHUNK);
  for (int e = e0 + threadIdx.x; e < e1; e += 1024) {
    int id = ids[e];
    if (id >= lo && id < hi) atomicAdd(&hist[id - lo], 1);  // LDS atomic
  }
  __syncthreads();
  int* dst = partial + ((size_t)a * NCHUNK + c) * N + lo;
  for (int i = threadIdx.x; i < len; i += 1024) dst[i] = hist[i];
}

// ---------- fused: reduce partials -> dinv/indeg, then in-block exscan ----------
__global__ __launch_bounds__(1024) void k_dinv_scan(const int* __restrict__ partial,
                                                    float* __restrict__ dinv,
                                                    int* __restrict__ indeg,
                                                    int* __restrict__ ptr,
                                                    int* __restrict__ bsum, int N) {
  __shared__ int s[1024];
  int g = blockIdx.x * 1024 + threadIdx.x;
  int deg = 0, ind = 0;
  if (g < N) {
#pragma unroll
    for (int c = 0; c < NCHUNK; ++c) {
      deg += partial[(size_t)c * N + g];
      ind += partial[((size_t)NCHUNK + c) * N + g];
    }
    dinv[g] = (deg > 0) ? (1.0f / sqrtf((float)deg)) : 0.0f;
    indeg[g] = ind;
  }
  s[threadIdx.x] = ind;
  __syncthreads();
  for (int off = 1; off < 1024; off <<= 1) {
    int tv = (threadIdx.x >= off) ? s[threadIdx.x - off] : 0;
    __syncthreads();
    s[threadIdx.x] += tv;
    __syncthreads();
  }
  if (g < N) ptr[g] = s[threadIdx.x] - ind;  // exclusive within block
  if (threadIdx.x == 1023) bsum[blockIdx.x] = s[1023];
}

// ---------- fused: scan bsum (in LDS) + finalize ptr + emit bases ----------
__global__ __launch_bounds__(256) void k_base(const int* __restrict__ partial,
                                              const int* __restrict__ bsum,
                                              int* __restrict__ ptr,
                                              int* __restrict__ base, int N, int nb) {
  __shared__ int pbs[64];
  if (threadIdx.x == 0) {
    int acc = 0;
    for (int i = 0; i < nb; ++i) { pbs[i] = acc; acc += bsum[i]; }
  }
  __syncthreads();
  int n = blockIdx.x * 256 + threadIdx.x;
  if (n >= N) return;
  int run = ptr[n] + pbs[n >> 10];
  ptr[n] = run;                      // final global exclusive scan
#pragma unroll
  for (int c = 0; c < NCHUNK; ++c) {
    base[(size_t)c * N + n] = run;
    run += partial[((size_t)NCHUNK + c) * N + n];
  }
}

// ---------- counting-sort binning (LDS atomics; base slice preloaded) ----------
__global__ __launch_bounds__(1024) void k_bin2(const int* __restrict__ ei,
                                               const int* __restrict__ base,
                                               int* __restrict__ csr_row,
                                               int N, int E, int range) {
  __shared__ int cnt[HIST_B];
  __shared__ int base_s[HIST_B];
  int c = blockIdx.x % NCHUNK;
  int r = blockIdx.x / NCHUNK;
  const int* row = ei;
  const int* col = ei + E;
  int lo = r * range;
  int hi = min(N, lo + range);
  int len = hi - lo;
  const int* bsrc = base + (size_t)c * N + lo;
  for (int i = threadIdx.x; i < len; i += 1024) {
    cnt[i] = 0;
    base_s[i] = bsrc[i];
  }
  __syncthreads();
  int e0 = (int)((long long)E * c / NCHUNK);
  int e1 = (int)((long long)E * (c + 1) / NCHUNK);
  for (int e = e0 + threadIdx.x; e < e1; e += 1024) {
    int cl = col[e];
    int rw = row[e];
    if (cl >= lo && cl < hi) {
      int off = atomicAdd(&cnt[cl - lo], 1);   // LDS atomic
      csr_row[base_s[cl - lo] + off] = rw;     // plain store (L2-absorbed)
    }
  }
}

// ---------- dual GEMM: t = (h@Wn)*dinv[row] (bf16), agg = h@Wi + bias ----------
// h and agg may ALIAS (in-place layer 2): block owns rows [64b,64b+64),
// stages each 32-row group into LDS before overwriting it; groups disjoint.
template <bool RELU>
__global__ __launch_bounds__(256) void k_dual_gemm(
    const float* h,
    const float* __restrict__ Wn,
    const float* __restrict__ Wi,
    const float* __restrict__ bias,
    const float* __restrict__ dinv,
    __hip_bfloat16* __restrict__ t, float* agg, int N) {
  __shared__ float Wn_s[64 * 64];
  __shared__ float Wi_s[64 * 64];
  __shared__ float b_s[64];
  __shared__ float h_s[32 * 68];   // 32 rows, stride 68 (pad kills store conflicts)

  const int tid = threadIdx.x;
  {
    const float4* Wn4 = (const float4*)Wn;
    const float4* Wi4 = (const float4*)Wi;
    for (int i = tid; i < 1024; i += 256) {
      ((float4*)Wn_s)[i] = Wn4[i];
      ((float4*)Wi_s)[i] = Wi4[i];
    }
  }
  if (tid < 64) b_s[tid] = bias[tid];

  const int j = tid & 63;      // output column
  const int rg = tid >> 6;     // row group 0..3 -> rows rg*8..rg*8+7
  const int r0 = blockIdx.x * 64;

  for (int g = 0; g < 2; ++g) {
    __syncthreads();  // protect h_s from prior readers; fences W staging (g=0)
    for (int v = tid; v < 512; v += 256) {
      int rr = v >> 4;
      int c4 = v & 15;
      int rload = r0 + g * 32 + rr;
      float4 val = make_float4(0.f, 0.f, 0.f, 0.f);
      if (rload < N) {
        val = *(const float4*)&h[(size_t)rload * 64 + c4 * 4];
        if (RELU) {
          val.x = fmaxf(val.x, 0.f); val.y = fmaxf(val.y, 0.f);
          val.z = fmaxf(val.z, 0.f); val.w = fmaxf(val.w, 0.f);
        }
      }
      *(float4*)&h_s[rr * 68 + c4 * 4] = val;
    }
    __syncthreads();

    float acc_t[8] = {0.f, 0.f, 0.f, 0.f, 0.f, 0.f, 0.f, 0.f};
    float acc_a[8] = {0.f, 0.f, 0.f, 0.f, 0.f, 0.f, 0.f, 0.f};
    for (int k4 = 0; k4 < 16; ++k4) {
      float4 hv[8];
#pragma unroll
      for (int r = 0; r < 8; ++r)
        hv[r] = *(const float4*)&h_s[(rg * 8 + r) * 68 + k4 * 4];
#pragma unroll
      for (int kk = 0; kk < 4; ++kk) {
        int k = k4 * 4 + kk;
        float wn = Wn_s[k * 64 + j];
        float wi = Wi_s[k * 64 + j];
#pragma unroll
        for (int r = 0; r < 8; ++r) {
          float hk = ((const float*)&hv[r])[kk];
          acc_t[r] = fmaf(hk, wn, acc_t[r]);
          acc_a[r] = fmaf(hk, wi, acc_a[r]);
        }
      }
    }
#pragma unroll
    for (int r = 0; r < 8; ++r) {
      int rr = r0 + g * 32 + rg * 8 + r;
      if (rr < N) {
        t[(size_t)rr * 64 + j] = __float2bfloat16(acc_t[r] * dinv[rr]);
        agg[(size_t)rr * 64 + j] = acc_a[r] + b_s[j];
      }
    }
  }
}

// ---------- CSR gather (layer 1): agg[n] += dinv[n] * sum_e t'[row_e] ----------
// One wave per node; quarter-wave per edge (16 lanes x bf16x4 = full 128B row),
// unrolled 2 -> 8 edges in flight. t pre-scaled by dinv[src]: pure-add loop.
__global__ __launch_bounds__(256) void k_gather(
    const int* __restrict__ csr_row, const int* __restrict__ ptr,
    const int* __restrict__ indeg, const float* __restrict__ dinv,
    const __hip_bfloat16* __restrict__ t, float* __restrict__ agg, int N) {
  int n = blockIdx.x * 4 + (threadIdx.x >> 6);
  if (n >= N) return;
  int lane = threadIdx.x & 63;
  int q = lane >> 4;
  int fl = lane & 15;
  int i0 = ptr[n];
  int end = i0 + indeg[n];
  float dn = dinv[n];

  float4 aggv = make_float4(0.f, 0.f, 0.f, 0.f);
  if (q == 0) aggv = *(const float4*)&agg[(size_t)n * 64 + 4 * fl];  // independent load

  float4 acc = make_float4(0.f, 0.f, 0.f, 0.f);
  int i = i0 + q;
  for (; i + 4 < end; i += 8) {
    int ra = csr_row[i];
    int rb = csr_row[i + 4];
    ushort4 ua = *(const ushort4*)&t[(size_t)ra * 64 + 4 * fl];
    ushort4 ub = *(const ushort4*)&t[(size_t)rb * 64 + 4 * fl];
    float4 va, vb;
    ((unsigned*)&va)[0] = (unsigned)ua.x << 16; ((unsigned*)&va)[1] = (unsigned)ua.y << 16;
    ((unsigned*)&va)[2] = (unsigned)ua.z << 16; ((unsigned*)&va)[3] = (unsigned)ua.w << 16;
    ((unsigned*)&vb)[0] = (unsigned)ub.x << 16; ((unsigned*)&vb)[1] = (unsigned)ub.y << 16;
    ((unsigned*)&vb)[2] = (unsigned)ub.z << 16; ((unsigned*)&vb)[3] = (unsigned)ub.w << 16;
    acc.x += va.x + vb.x; acc.y += va.y + vb.y;
    acc.z += va.z + vb.z; acc.w += va.w + vb.w;
  }
  for (; i < end; i += 4) {
    int ra = csr_row[i];
    ushort4 ua = *(const ushort4*)&t[(size_t)ra * 64 + 4 * fl];
    float4 va;
    ((unsigned*)&va)[0] = (unsigned)ua.x << 16; ((unsigned*)&va)[1] = (unsigned)ua.y << 16;
    ((unsigned*)&va)[2] = (unsigned)ua.z << 16; ((unsigned*)&va)[3] = (unsigned)ua.w << 16;
    acc.x += va.x; acc.y += va.y; acc.z += va.z; acc.w += va.w;
  }
  acc.x += __shfl_xor(acc.x, 16); acc.y += __shfl_xor(acc.y, 16);
  acc.z += __shfl_xor(acc.z, 16); acc.w += __shfl_xor(acc.w, 16);
  acc.x += __shfl_xor(acc.x, 32); acc.y += __shfl_xor(acc.y, 32);
  acc.z += __shfl_xor(acc.z, 32); acc.w += __shfl_xor(acc.w, 32);
  if (q == 0) {
    aggv.x += dn * acc.x; aggv.y += dn * acc.y;
    aggv.z += dn * acc.z; aggv.w += dn * acc.w;
    *(float4*)&agg[(size_t)n * 64 + 4 * fl] = aggv;
  }
}

// ---------- FUSED layer-2 gather + output GEMM (round-10 proven structure) ----------
__global__ __launch_bounds__(256) void k_gather_out(
    const int* __restrict__ csr_row, const int* __restrict__ ptr,
    const int* __restrict__ indeg, const float* __restrict__ dinv,
    const __hip_bfloat16* __restrict__ t, const float* __restrict__ agg,
    const float* __restrict__ Wo,   // [64,32]
    const float* __restrict__ bo,   // [32]
    float* __restrict__ out, int N) {
  __shared__ float Wo_s[64 * 32];
  __shared__ float bo_s[32];
  __shared__ float rowbuf[4][64];

  const int tid = threadIdx.x;
  for (int i = tid; i < 2048; i += 256) Wo_s[i] = Wo[i];
  if (tid < 32) bo_s[tid] = bo[tid];
  __syncthreads();   // barrier BEFORE any divergent exit

  int w = tid >> 6;                 // wave id 0..3
  int n = blockIdx.x * 4 + w;
  if (n >= N) return;
  int lane = tid & 63;
  int q = lane >> 4;
  int fl = lane & 15;
  int i0 = ptr[n];
  int end = i0 + indeg[n];
  float dn = dinv[n];

  float4 aggv = make_float4(0.f, 0.f, 0.f, 0.f);
  if (q == 0) aggv = *(const float4*)&agg[(size_t)n * 64 + 4 * fl];

  float4 acc = make_float4(0.f, 0.f, 0.f, 0.f);
  int i = i0 + q;
  for (; i + 4 < end; i += 8) {
    int ra = csr_row[i];
    int rb = csr_row[i + 4];
    ushort4 ua = *(const ushort4*)&t[(size_t)ra * 64 + 4 * fl];
    ushort4 ub = *(const ushort4*)&t[(size_t)rb * 64 + 4 * fl];
    float4 va, vb;
    ((unsigned*)&va)[0] = (unsigned)ua.x << 16; ((unsigned*)&va)[1] = (unsigned)ua.y << 16;
    ((unsigned*)&va)[2] = (unsigned)ua.z << 16; ((unsigned*)&va)[3] = (unsigned)ua.w << 16;
    ((unsigned*)&vb)[0] = (unsigned)ub.x << 16; ((unsigned*)&vb)[1] = (unsigned)ub.y << 16;
    ((unsigned*)&vb)[2] = (unsigned)ub.z << 16; ((unsigned*)&vb)[3] = (unsigned)ub.w << 16;
    acc.x += va.x + vb.x; acc.y += va.y + vb.y;
    acc.z += va.z + vb.z; acc.w += va.w + vb.w;
  }
  for (; i < end; i += 4) {
    int ra = csr_row[i];
    ushort4 ua = *(const ushort4*)&t[(size_t)ra * 64 + 4 * fl];
    float4 va;
    ((unsigned*)&va)[0] = (unsigned)ua.x << 16; ((unsigned*)&va)[1] = (unsigned)ua.y << 16;
    ((unsigned*)&va)[2] = (unsigned)ua.z << 16; ((unsigned*)&va)[3] = (unsigned)ua.w << 16;
    acc.x += va.x; acc.y += va.y; acc.z += va.z; acc.w += va.w;
  }
  acc.x += __shfl_xor(acc.x, 16); acc.y += __shfl_xor(acc.y, 16);
  acc.z += __shfl_xor(acc.z, 16); acc.w += __shfl_xor(acc.w, 16);
  acc.x += __shfl_xor(acc.x, 32); acc.y += __shfl_xor(acc.y, 32);
  acc.z += __shfl_xor(acc.z, 32); acc.w += __shfl_xor(acc.w, 32);
  if (q == 0) {
    rowbuf[w][4 * fl + 0] = fmaxf(aggv.x + dn * acc.x, 0.f);
    rowbuf[w][4 * fl + 1] = fmaxf(aggv.y + dn * acc.y, 0.f);
    rowbuf[w][4 * fl + 2] = fmaxf(aggv.z + dn * acc.z, 0.f);
    rowbuf[w][4 * fl + 3] = fmaxf(aggv.w + dn * acc.w, 0.f);
  }
  // same-wave LDS RAW: compiler inserts lgkmcnt wait; no barrier needed.
  int half = lane >> 5;      // k-range half
  int j = lane & 31;         // output column
  float ov = 0.f;
#pragma unroll 8
  for (int k = 32 * half; k < 32 * half + 32; ++k)
    ov = fmaf(rowbuf[w][k], Wo_s[k * 32 + j], ov);
  ov += __shfl_xor(ov, 32);
  if (half == 0) out[(size_t)n * 32 + j] = ov + bo_s[j];
}

extern "C" void kernel_launch(void* const* d_in, const int* in_sizes, int n_in,
                              void* d_out, int out_size, void* d_ws, size_t ws_size,
                              hipStream_t stream) {
  const float* x = (const float*)d_in[0];
  const int* ei = (const int*)d_in[1];
  const float* W_in1 = (const float*)d_in[2];
  const float* W_neigh1 = (const float*)d_in[3];
  const float* bias1 = (const float*)d_in[4];
  const float* W_in2 = (const float*)d_in[5];
  const float* W_neigh2 = (const float*)d_in[6];
  const float* bias2 = (const float*)d_in[7];
  const float* W_out = (const float*)d_in[8];
  const float* b_out = (const float*)d_in[9];
  float* out = (float*)d_out;

  const int N = in_sizes[0] / 64;
  const int E = in_sizes[1] / 2;

  char* ws = (char*)d_ws;
  size_t off = 0;
  auto alloc = [&](size_t bytes) -> void* {
    void* p = ws + off;
    off += (bytes + 255) & ~(size_t)255;
    return p;
  };
  float* dinv = (float*)alloc((size_t)N * 4);
  int* indeg = (int*)alloc((size_t)N * 4);
  int* ptr = (int*)alloc((size_t)N * 4);
  int* bsum = (int*)alloc(256);
  int* csr_row = (int*)alloc((size_t)E * 4);
  int* partial = (int*)alloc((size_t)2 * NCHUNK * N * 4);
  int* base = (int*)alloc((size_t)NCHUNK * N * 4);
  __hip_bfloat16* t = (__hip_bfloat16*)alloc((size_t)N * 64 * 2);
  float* agg = (float*)alloc((size_t)N * 64 * 4);
  (void)ws_size;

  int range_h = (N + NRANGE_H - 1) / NRANGE_H;  // 12500 <= HIST_H
  int range_b = (N + NRANGE_B - 1) / NRANGE_B;  // 6250  <= HIST_B
  int gN = (N + 255) / 256;
  int gRows = (N + 63) / 64;
  int gNode = (N + 3) / 4;
  int nb = (N + 1023) / 1024;

  k_hist<<<2 * NRANGE_H * NCHUNK, 1024, 0, stream>>>(ei, partial, N, E, range_h);
  k_dinv_scan<<<nb, 1024, 0, stream>>>(partial, dinv, indeg, ptr, bsum, N);
  k_base<<<gN, 256, 0, stream>>>(partial, bsum, ptr, base, N, nb);
  k_bin2<<<NRANGE_B * NCHUNK, 1024, 0, stream>>>(ei, base, csr_row, N, E, range_b);

  // layer 1
  k_dual_gemm<false><<<gRows, 256, 0, stream>>>(x, W_neigh1, W_in1, bias1, dinv, t, agg, N);
  k_gather<<<gNode, 256, 0, stream>>>(csr_row, ptr, indeg, dinv, t, agg, N);

  // layer 2 (in-place on agg), then fused gather+output
  k_dual_gemm<true><<<gRows, 256, 0, stream>>>(agg, W_neigh2, W_in2, bias2, dinv, t, agg, N);
  k_gather_out<<<gNode, 256, 0, stream>>>(csr_row, ptr, indeg, dinv, t, agg,
                                          W_out, b_out, out, N);
}

// Round 14
// 204.150 us; speedup vs baseline: 1.3110x; 1.1480x over previous
//
#include <hip/hip_runtime.h>
#include <hip/hip_bf16.h>

// Pipeline (no global atomics — they write through to HBM per-op on MI355X;
// rounds 3/4). Build needs >=256 blocks + multi-block scans (rounds 5/7).
// Gathers are at a per-CU outstanding-miss floor (~44 us each; r11 deeper
// pipelining was null, FETCH pinned at ~41 MB). Round 14: dual GEMMs moved
// to 16x16x32 bf16 MFMA (fp32 VALU was the cost, not memory: 32 MB traffic
// = 5 us floor vs ~23 us measured). Layouts: A[m=lane&15][k=quad*8+j],
// B[k=quad*8+j][n=lane&15], C/D col=lane&15 row=quad*4+reg (guide-verified).

#define NCHUNK 32     // edge chunks
#define NRANGE_H 4    // hist node ranges (range = 12500)
#define HIST_H 12544
#define NRANGE_B 8    // bin2 node ranges (range = 6250; needs 2 LDS arrays)
#define HIST_B 6272

typedef __attribute__((ext_vector_type(8))) short bfrag;   // 8 bf16 = 4 VGPRs
typedef __attribute__((ext_vector_type(4))) float f32x4;

// ---------- partial histograms: a=0 deg over row, a=1 indeg over col ----------
__global__ __launch_bounds__(1024) void k_hist(const int* __restrict__ ei,
                                               int* __restrict__ partial,
                                               int N, int E, int range) {
  __shared__ int hist[HIST_H];
  int c = blockIdx.x % NCHUNK;
  int r = (blockIdx.x / NCHUNK) % NRANGE_H;
  int a = blockIdx.x / (NCHUNK * NRANGE_H);
  const int* ids = ei + (size_t)a * E;
  int lo = r * range;
  int hi = min(N, lo + range);
  int len = hi - lo;
  for (int i = threadIdx.x; i < len; i += 1024) hist[i] = 0;
  __syncthreads();
  int e0 = (int)((long long)E * c / NCHUNK);
  int e1 = (int)((long long)E * (c + 1) / NCHUNK);
  for (int e = e0 + threadIdx.x; e < e1; e += 1024) {
    int id = ids[e];
    if (id >= lo && id < hi) atomicAdd(&hist[id - lo], 1);  // LDS atomic
  }
  __syncthreads();
  int* dst = partial + ((size_t)a * NCHUNK + c) * N + lo;
  for (int i = threadIdx.x; i < len; i += 1024) dst[i] = hist[i];
}

// ---------- fused: reduce partials -> dinv/indeg, then in-block exscan ----------
__global__ __launch_bounds__(1024) void k_dinv_scan(const int* __restrict__ partial,
                                                    float* __restrict__ dinv,
                                                    int* __restrict__ indeg,
                                                    int* __restrict__ ptr,
                                                    int* __restrict__ bsum, int N) {
  __shared__ int s[1024];
  int g = blockIdx.x * 1024 + threadIdx.x;
  int deg = 0, ind = 0;
  if (g < N) {
#pragma unroll
    for (int c = 0; c < NCHUNK; ++c) {
      deg += partial[(size_t)c * N + g];
      ind += partial[((size_t)NCHUNK + c) * N + g];
    }
    dinv[g] = (deg > 0) ? (1.0f / sqrtf((float)deg)) : 0.0f;
    indeg[g] = ind;
  }
  s[threadIdx.x] = ind;
  __syncthreads();
  for (int off = 1; off < 1024; off <<= 1) {
    int tv = (threadIdx.x >= off) ? s[threadIdx.x - off] : 0;
    __syncthreads();
    s[threadIdx.x] += tv;
    __syncthreads();
  }
  if (g < N) ptr[g] = s[threadIdx.x] - ind;  // exclusive within block
  if (threadIdx.x == 1023) bsum[blockIdx.x] = s[1023];
}

// ---------- fused: scan bsum (in LDS) + finalize ptr + emit bases ----------
__global__ __launch_bounds__(256) void k_base(const int* __restrict__ partial,
                                              const int* __restrict__ bsum,
                                              int* __restrict__ ptr,
                                              int* __restrict__ base, int N, int nb) {
  __shared__ int pbs[64];
  if (threadIdx.x == 0) {
    int acc = 0;
    for (int i = 0; i < nb; ++i) { pbs[i] = acc; acc += bsum[i]; }
  }
  __syncthreads();
  int n = blockIdx.x * 256 + threadIdx.x;
  if (n >= N) return;
  int run = ptr[n] + pbs[n >> 10];
  ptr[n] = run;                      // final global exclusive scan
#pragma unroll
  for (int c = 0; c < NCHUNK; ++c) {
    base[(size_t)c * N + n] = run;
    run += partial[((size_t)NCHUNK + c) * N + n];
  }
}

// ---------- counting-sort binning (LDS atomics; base slice preloaded) ----------
__global__ __launch_bounds__(1024) void k_bin2(const int* __restrict__ ei,
                                               const int* __restrict__ base,
                                               int* __restrict__ csr_row,
                                               int N, int E, int range) {
  __shared__ int cnt[HIST_B];
  __shared__ int base_s[HIST_B];
  int c = blockIdx.x % NCHUNK;
  int r = blockIdx.x / NCHUNK;
  const int* row = ei;
  const int* col = ei + E;
  int lo = r * range;
  int hi = min(N, lo + range);
  int len = hi - lo;
  const int* bsrc = base + (size_t)c * N + lo;
  for (int i = threadIdx.x; i < len; i += 1024) {
    cnt[i] = 0;
    base_s[i] = bsrc[i];
  }
  __syncthreads();
  int e0 = (int)((long long)E * c / NCHUNK);
  int e1 = (int)((long long)E * (c + 1) / NCHUNK);
  for (int e = e0 + threadIdx.x; e < e1; e += 1024) {
    int cl = col[e];
    int rw = row[e];
    if (cl >= lo && cl < hi) {
      int off = atomicAdd(&cnt[cl - lo], 1);   // LDS atomic
      csr_row[base_s[cl - lo] + off] = rw;     // plain store (L2-absorbed)
    }
  }
}

// ---------- MFMA dual GEMM: t = (h@Wn)*dinv[row] (bf16), agg = h@Wi + bias ----------
// 16x16x32 bf16 MFMA. Block = 4 waves x 16-row tiles = 64 rows.
// h and agg may ALIAS (layer 2 in place): each wave reads only its own 16
// rows into A-regs; stores depend on MFMA results which depend on those
// loads, so all reads precede all writes. Waves/blocks touch disjoint rows.
template <bool RELU>
__global__ __launch_bounds__(256) void k_dual_gemm_mfma(
    const float* h,
    const float* __restrict__ Wn,
    const float* __restrict__ Wi,
    const float* __restrict__ bias,
    const float* __restrict__ dinv,
    __hip_bfloat16* __restrict__ t, float* agg, int N) {
  __shared__ short Wn_s[64 * 66];   // stride 66: quads land on banks 0/8/16/24
  __shared__ short Wi_s[64 * 66];
  __shared__ float b_s[64];

  const int tid = threadIdx.x;
  for (int i = tid; i < 4096; i += 256) {
    int k = i >> 6, n = i & 63;
    __hip_bfloat16 a = __float2bfloat16(Wn[i]);
    __hip_bfloat16 b = __float2bfloat16(Wi[i]);
    Wn_s[k * 66 + n] = *(short*)&a;
    Wi_s[k * 66 + n] = *(short*)&b;
  }
  if (tid < 64) b_s[tid] = bias[tid];
  __syncthreads();

  const int lane = tid & 63;
  const int w = tid >> 6;
  const int m = lane & 15;       // A row within tile / B col within col-tile
  const int quad = lane >> 4;    // 0..3

  // B fragments in registers: B[k = kb*32 + quad*8 + j][n = ct*16 + m]
  bfrag Bn[4][2], Bi[4][2];
#pragma unroll
  for (int ct = 0; ct < 4; ++ct)
#pragma unroll
    for (int kb = 0; kb < 2; ++kb) {
      bfrag vn, vi;
#pragma unroll
      for (int j = 0; j < 8; ++j) {
        int k = kb * 32 + quad * 8 + j;
        int n = ct * 16 + m;
        vn[j] = Wn_s[k * 66 + n];
        vi[j] = Wi_s[k * 66 + n];
      }
      Bn[ct][kb] = vn;
      Bi[ct][kb] = vi;
    }

  const int r0 = blockIdx.x * 64 + w * 16;   // this wave's 16-row tile
  const int arow = r0 + m;

  // A fragments: A[m][k = kb*32 + quad*8 + j] from fp32 h (relu fused)
  bfrag A[2];
#pragma unroll
  for (int kb = 0; kb < 2; ++kb) {
    bfrag av = {};
    if (arow < N) {
      const float* src = &h[(size_t)arow * 64 + kb * 32 + quad * 8];
      float4 f0 = *(const float4*)src;
      float4 f1 = *(const float4*)(src + 4);
      float tmp[8] = {f0.x, f0.y, f0.z, f0.w, f1.x, f1.y, f1.z, f1.w};
#pragma unroll
      for (int j = 0; j < 8; ++j) {
        float v = RELU ? fmaxf(tmp[j], 0.f) : tmp[j];
        __hip_bfloat16 hb = __float2bfloat16(v);
        av[j] = *(short*)&hb;
      }
    }
    A[kb] = av;
  }

  f32x4 accT[4], accA[4];
#pragma unroll
  for (int ct = 0; ct < 4; ++ct) {
    f32x4 z = {0.f, 0.f, 0.f, 0.f};
    accT[ct] = z;
    accA[ct] = z;
  }
#pragma unroll
  for (int ct = 0; ct < 4; ++ct) {
    accT[ct] = __builtin_amdgcn_mfma_f32_16x16x32_bf16(A[0], Bn[ct][0], accT[ct], 0, 0, 0);
    accT[ct] = __builtin_amdgcn_mfma_f32_16x16x32_bf16(A[1], Bn[ct][1], accT[ct], 0, 0, 0);
    accA[ct] = __builtin_amdgcn_mfma_f32_16x16x32_bf16(A[0], Bi[ct][0], accA[ct], 0, 0, 0);
    accA[ct] = __builtin_amdgcn_mfma_f32_16x16x32_bf16(A[1], Bi[ct][1], accA[ct], 0, 0, 0);
  }

  // epilogue: C/D row = quad*4 + reg, col = ct*16 + m
#pragma unroll
  for (int reg = 0; reg < 4; ++reg) {
    int r = r0 + quad * 4 + reg;
    if (r < N) {
      float dv = dinv[r];
#pragma unroll
      for (int ct = 0; ct < 4; ++ct) {
        int col = ct * 16 + m;
        t[(size_t)r * 64 + col] = __float2bfloat16(accT[ct][reg] * dv);
        agg[(size_t)r * 64 + col] = accA[ct][reg] + b_s[col];
      }
    }
  }
}

// ---------- CSR gather (layer 1): agg[n] += dinv[n] * sum_e t'[row_e] ----------
// One wave per node; quarter-wave per edge; t pre-scaled by dinv[src].
__global__ __launch_bounds__(256) void k_gather(
    const int* __restrict__ csr_row, const int* __restrict__ ptr,
    const int* __restrict__ indeg, const float* __restrict__ dinv,
    const __hip_bfloat16* __restrict__ t, float* __restrict__ agg, int N) {
  int n = blockIdx.x * 4 + (threadIdx.x >> 6);
  if (n >= N) return;
  int lane = threadIdx.x & 63;
  int q = lane >> 4;
  int fl = lane & 15;
  int i0 = ptr[n];
  int end = i0 + indeg[n];
  float dn = dinv[n];

  float4 aggv = make_float4(0.f, 0.f, 0.f, 0.f);
  if (q == 0) aggv = *(const float4*)&agg[(size_t)n * 64 + 4 * fl];

  float4 acc = make_float4(0.f, 0.f, 0.f, 0.f);
  int i = i0 + q;
  for (; i + 4 < end; i += 8) {
    int ra = csr_row[i];
    int rb = csr_row[i + 4];
    ushort4 ua = *(const ushort4*)&t[(size_t)ra * 64 + 4 * fl];
    ushort4 ub = *(const ushort4*)&t[(size_t)rb * 64 + 4 * fl];
    float4 va, vb;
    ((unsigned*)&va)[0] = (unsigned)ua.x << 16; ((unsigned*)&va)[1] = (unsigned)ua.y << 16;
    ((unsigned*)&va)[2] = (unsigned)ua.z << 16; ((unsigned*)&va)[3] = (unsigned)ua.w << 16;
    ((unsigned*)&vb)[0] = (unsigned)ub.x << 16; ((unsigned*)&vb)[1] = (unsigned)ub.y << 16;
    ((unsigned*)&vb)[2] = (unsigned)ub.z << 16; ((unsigned*)&vb)[3] = (unsigned)ub.w << 16;
    acc.x += va.x + vb.x; acc.y += va.y + vb.y;
    acc.z += va.z + vb.z; acc.w += va.w + vb.w;
  }
  for (; i < end; i += 4) {
    int ra = csr_row[i];
    ushort4 ua = *(const ushort4*)&t[(size_t)ra * 64 + 4 * fl];
    float4 va;
    ((unsigned*)&va)[0] = (unsigned)ua.x << 16; ((unsigned*)&va)[1] = (unsigned)ua.y << 16;
    ((unsigned*)&va)[2] = (unsigned)ua.z << 16; ((unsigned*)&va)[3] = (unsigned)ua.w << 16;
    acc.x += va.x; acc.y += va.y; acc.z += va.z; acc.w += va.w;
  }
  acc.x += __shfl_xor(acc.x, 16); acc.y += __shfl_xor(acc.y, 16);
  acc.z += __shfl_xor(acc.z, 16); acc.w += __shfl_xor(acc.w, 16);
  acc.x += __shfl_xor(acc.x, 32); acc.y += __shfl_xor(acc.y, 32);
  acc.z += __shfl_xor(acc.z, 32); acc.w += __shfl_xor(acc.w, 32);
  if (q == 0) {
    aggv.x += dn * acc.x; aggv.y += dn * acc.y;
    aggv.z += dn * acc.z; aggv.w += dn * acc.w;
    *(float4*)&agg[(size_t)n * 64 + 4 * fl] = aggv;
  }
}

// ---------- FUSED layer-2 gather + output GEMM (round-10 proven structure) ----------
__global__ __launch_bounds__(256) void k_gather_out(
    const int* __restrict__ csr_row, const int* __restrict__ ptr,
    const int* __restrict__ indeg, const float* __restrict__ dinv,
    const __hip_bfloat16* __restrict__ t, const float* __restrict__ agg,
    const float* __restrict__ Wo,   // [64,32]
    const float* __restrict__ bo,   // [32]
    float* __restrict__ out, int N) {
  __shared__ float Wo_s[64 * 32];
  __shared__ float bo_s[32];
  __shared__ float rowbuf[4][64];

  const int tid = threadIdx.x;
  for (int i = tid; i < 2048; i += 256) Wo_s[i] = Wo[i];
  if (tid < 32) bo_s[tid] = bo[tid];
  __syncthreads();   // barrier BEFORE any divergent exit

  int w = tid >> 6;                 // wave id 0..3
  int n = blockIdx.x * 4 + w;
  if (n >= N) return;
  int lane = tid & 63;
  int q = lane >> 4;
  int fl = lane & 15;
  int i0 = ptr[n];
  int end = i0 + indeg[n];
  float dn = dinv[n];

  float4 aggv = make_float4(0.f, 0.f, 0.f, 0.f);
  if (q == 0) aggv = *(const float4*)&agg[(size_t)n * 64 + 4 * fl];

  float4 acc = make_float4(0.f, 0.f, 0.f, 0.f);
  int i = i0 + q;
  for (; i + 4 < end; i += 8) {
    int ra = csr_row[i];
    int rb = csr_row[i + 4];
    ushort4 ua = *(const ushort4*)&t[(size_t)ra * 64 + 4 * fl];
    ushort4 ub = *(const ushort4*)&t[(size_t)rb * 64 + 4 * fl];
    float4 va, vb;
    ((unsigned*)&va)[0] = (unsigned)ua.x << 16; ((unsigned*)&va)[1] = (unsigned)ua.y << 16;
    ((unsigned*)&va)[2] = (unsigned)ua.z << 16; ((unsigned*)&va)[3] = (unsigned)ua.w << 16;
    ((unsigned*)&vb)[0] = (unsigned)ub.x << 16; ((unsigned*)&vb)[1] = (unsigned)ub.y << 16;
    ((unsigned*)&vb)[2] = (unsigned)ub.z << 16; ((unsigned*)&vb)[3] = (unsigned)ub.w << 16;
    acc.x += va.x + vb.x; acc.y += va.y + vb.y;
    acc.z += va.z + vb.z; acc.w += va.w + vb.w;
  }
  for (; i < end; i += 4) {
    int ra = csr_row[i];
    ushort4 ua = *(const ushort4*)&t[(size_t)ra * 64 + 4 * fl];
    float4 va;
    ((unsigned*)&va)[0] = (unsigned)ua.x << 16; ((unsigned*)&va)[1] = (unsigned)ua.y << 16;
    ((unsigned*)&va)[2] = (unsigned)ua.z << 16; ((unsigned*)&va)[3] = (unsigned)ua.w << 16;
    acc.x += va.x; acc.y += va.y; acc.z += va.z; acc.w += va.w;
  }
  acc.x += __shfl_xor(acc.x, 16); acc.y += __shfl_xor(acc.y, 16);
  acc.z += __shfl_xor(acc.z, 16); acc.w += __shfl_xor(acc.w, 16);
  acc.x += __shfl_xor(acc.x, 32); acc.y += __shfl_xor(acc.y, 32);
  acc.z += __shfl_xor(acc.z, 32); acc.w += __shfl_xor(acc.w, 32);
  if (q == 0) {
    rowbuf[w][4 * fl + 0] = fmaxf(aggv.x + dn * acc.x, 0.f);
    rowbuf[w][4 * fl + 1] = fmaxf(aggv.y + dn * acc.y, 0.f);
    rowbuf[w][4 * fl + 2] = fmaxf(aggv.z + dn * acc.z, 0.f);
    rowbuf[w][4 * fl + 3] = fmaxf(aggv.w + dn * acc.w, 0.f);
  }
  // same-wave LDS RAW: compiler inserts lgkmcnt wait; no barrier needed.
  int half = lane >> 5;      // k-range half
  int j = lane & 31;         // output column
  float ov = 0.f;
#pragma unroll 8
  for (int k = 32 * half; k < 32 * half + 32; ++k)
    ov = fmaf(rowbuf[w][k], Wo_s[k * 32 + j], ov);
  ov += __shfl_xor(ov, 32);
  if (half == 0) out[(size_t)n * 32 + j] = ov + bo_s[j];
}

extern "C" void kernel_launch(void* const* d_in, const int* in_sizes, int n_in,
                              void* d_out, int out_size, void* d_ws, size_t ws_size,
                              hipStream_t stream) {
  const float* x = (const float*)d_in[0];
  const int* ei = (const int*)d_in[1];
  const float* W_in1 = (const float*)d_in[2];
  const float* W_neigh1 = (const float*)d_in[3];
  const float* bias1 = (const float*)d_in[4];
  const float* W_in2 = (const float*)d_in[5];
  const float* W_neigh2 = (const float*)d_in[6];
  const float* bias2 = (const float*)d_in[7];
  const float* W_out = (const float*)d_in[8];
  const float* b_out = (const float*)d_in[9];
  float* out = (float*)d_out;

  const int N = in_sizes[0] / 64;
  const int E = in_sizes[1] / 2;

  char* ws = (char*)d_ws;
  size_t off = 0;
  auto alloc = [&](size_t bytes) -> void* {
    void* p = ws + off;
    off += (bytes + 255) & ~(size_t)255;
    return p;
  };
  float* dinv = (float*)alloc((size_t)N * 4);
  int* indeg = (int*)alloc((size_t)N * 4);
  int* ptr = (int*)alloc((size_t)N * 4);
  int* bsum = (int*)alloc(256);
  int* csr_row = (int*)alloc((size_t)E * 4);
  int* partial = (int*)alloc((size_t)2 * NCHUNK * N * 4);
  int* base = (int*)alloc((size_t)NCHUNK * N * 4);
  __hip_bfloat16* t = (__hip_bfloat16*)alloc((size_t)N * 64 * 2);
  float* agg = (float*)alloc((size_t)N * 64 * 4);
  (void)ws_size;

  int range_h = (N + NRANGE_H - 1) / NRANGE_H;  // 12500 <= HIST_H
  int range_b = (N + NRANGE_B - 1) / NRANGE_B;  // 6250  <= HIST_B
  int gN = (N + 255) / 256;
  int gRows = (N + 63) / 64;
  int gNode = (N + 3) / 4;
  int nb = (N + 1023) / 1024;

  k_hist<<<2 * NRANGE_H * NCHUNK, 1024, 0, stream>>>(ei, partial, N, E, range_h);
  k_dinv_scan<<<nb, 1024, 0, stream>>>(partial, dinv, indeg, ptr, bsum, N);
  k_base<<<gN, 256, 0, stream>>>(partial, bsum, ptr, base, N, nb);
  k_bin2<<<NRANGE_B * NCHUNK, 1024, 0, stream>>>(ei, base, csr_row, N, E, range_b);

  // layer 1 (MFMA)
  k_dual_gemm_mfma<false><<<gRows, 256, 0, stream>>>(x, W_neigh1, W_in1, bias1, dinv, t, agg, N);
  k_gather<<<gNode, 256, 0, stream>>>(csr_row, ptr, indeg, dinv, t, agg, N);

  // layer 2 (MFMA, in-place on agg), then fused gather+output
  k_dual_gemm_mfma<true><<<gRows, 256, 0, stream>>>(agg, W_neigh2, W_in2, bias2, dinv, t, agg, N);
  k_gather_out<<<gNode, 256, 0, stream>>>(csr_row, ptr, indeg, dinv, t, agg,
                                          W_out, b_out, out, N);
}

// Round 15
// 203.149 us; speedup vs baseline: 1.3175x; 1.0049x over previous
//
#include <hip/hip_runtime.h>
#include <hip/hip_bf16.h>

// Pipeline (no global atomics — write through to HBM per-op; rounds 3/4).
// Build needs >=256 blocks / >=100K threads (rounds 5/7). Gathers are at the
// compulsory-miss x random-BW floor (~41MB FETCH, ~44us; r11/r12/r13 evidence)
// — leave them. Round 15: (a) MFMA W staged in FRAGMENT ORDER (1 ds_read_b128
// per frag vs 64 ds_read_u16), (b) bin2 NRANGE 8->4 (edge re-reads halved,
// cnt-only 50KB LDS, base from L2).

#define NCHUNK 32     // edge chunks
#define NRANGE_H 4    // hist node ranges (range = 12500)
#define HIST_H 12544
#define NRANGE_B 4    // bin2 node ranges (range = 12500)
#define HIST_B2 12544

typedef __attribute__((ext_vector_type(8))) short bfrag;   // 8 bf16 = 4 VGPRs
typedef __attribute__((ext_vector_type(4))) float f32x4;

// ---------- partial histograms: a=0 deg over row, a=1 indeg over col ----------
__global__ __launch_bounds__(1024) void k_hist(const int* __restrict__ ei,
                                               int* __restrict__ partial,
                                               int N, int E, int range) {
  __shared__ int hist[HIST_H];
  int c = blockIdx.x % NCHUNK;
  int r = (blockIdx.x / NCHUNK) % NRANGE_H;
  int a = blockIdx.x / (NCHUNK * NRANGE_H);
  const int* ids = ei + (size_t)a * E;
  int lo = r * range;
  int hi = min(N, lo + range);
  int len = hi - lo;
  for (int i = threadIdx.x; i < len; i += 1024) hist[i] = 0;
  __syncthreads();
  int e0 = (int)((long long)E * c / NCHUNK);
  int e1 = (int)((long long)E * (c + 1) / NCHUNK);
  for (int e = e0 + threadIdx.x; e < e1; e += 1024) {
    int id = ids[e];
    if (id >= lo && id < hi) atomicAdd(&hist[id - lo], 1);  // LDS atomic
  }
  __syncthreads();
  int* dst = partial + ((size_t)a * NCHUNK + c) * N + lo;
  for (int i = threadIdx.x; i < len; i += 1024) dst[i] = hist[i];
}

// ---------- fused: reduce partials -> dinv/indeg, then in-block exscan ----------
__global__ __launch_bounds__(1024) void k_dinv_scan(const int* __restrict__ partial,
                                                    float* __restrict__ dinv,
                                                    int* __restrict__ indeg,
                                                    int* __restrict__ ptr,
                                                    int* __restrict__ bsum, int N) {
  __shared__ int s[1024];
  int g = blockIdx.x * 1024 + threadIdx.x;
  int deg = 0, ind = 0;
  if (g < N) {
#pragma unroll
    for (int c = 0; c < NCHUNK; ++c) {
      deg += partial[(size_t)c * N + g];
      ind += partial[((size_t)NCHUNK + c) * N + g];
    }
    dinv[g] = (deg > 0) ? (1.0f / sqrtf((float)deg)) : 0.0f;
    indeg[g] = ind;
  }
  s[threadIdx.x] = ind;
  __syncthreads();
  for (int off = 1; off < 1024; off <<= 1) {
    int tv = (threadIdx.x >= off) ? s[threadIdx.x - off] : 0;
    __syncthreads();
    s[threadIdx.x] += tv;
    __syncthreads();
  }
  if (g < N) ptr[g] = s[threadIdx.x] - ind;  // exclusive within block
  if (threadIdx.x == 1023) bsum[blockIdx.x] = s[1023];
}

// ---------- fused: scan bsum (in LDS) + finalize ptr + emit bases ----------
__global__ __launch_bounds__(256) void k_base(const int* __restrict__ partial,
                                              const int* __restrict__ bsum,
                                              int* __restrict__ ptr,
                                              int* __restrict__ base, int N, int nb) {
  __shared__ int pbs[64];
  if (threadIdx.x == 0) {
    int acc = 0;
    for (int i = 0; i < nb; ++i) { pbs[i] = acc; acc += bsum[i]; }
  }
  __syncthreads();
  int n = blockIdx.x * 256 + threadIdx.x;
  if (n >= N) return;
  int run = ptr[n] + pbs[n >> 10];
  ptr[n] = run;                      // final global exclusive scan
#pragma unroll
  for (int c = 0; c < NCHUNK; ++c) {
    base[(size_t)c * N + n] = run;
    run += partial[((size_t)NCHUNK + c) * N + n];
  }
}

// ---------- counting-sort binning (LDS atomics on cnt; base from L2) ----------
__global__ __launch_bounds__(1024) void k_bin2(const int* __restrict__ ei,
                                               const int* __restrict__ base,
                                               int* __restrict__ csr_row,
                                               int N, int E, int range) {
  __shared__ int cnt[HIST_B2];   // 50 KB
  int c = blockIdx.x % NCHUNK;
  int r = blockIdx.x / NCHUNK;
  const int* row = ei;
  const int* col = ei + E;
  int lo = r * range;
  int hi = min(N, lo + range);
  int len = hi - lo;
  for (int i = threadIdx.x; i < len; i += 1024) cnt[i] = 0;
  __syncthreads();
  int e0 = (int)((long long)E * c / NCHUNK);
  int e1 = (int)((long long)E * (c + 1) / NCHUNK);
  const int* bslice = base + (size_t)c * N;
  for (int e = e0 + threadIdx.x; e < e1; e += 1024) {
    int cl = col[e];
    int rw = row[e];
    if (cl >= lo && cl < hi) {
      int off = atomicAdd(&cnt[cl - lo], 1);   // LDS atomic
      csr_row[bslice[cl] + off] = rw;          // base in L2; plain store
    }
  }
}

// ---------- MFMA dual GEMM: t = (h@Wn)*dinv[row] (bf16), agg = h@Wi + bias ----------
// 16x16x32 bf16 MFMA; W staged in FRAGMENT ORDER: frag (ct,kb) occupies
// shorts [((ct*2+kb)*64 + lane)*8 .. +8) so each lane's B-frag is one
// aligned ds_read_b128. h/agg may ALIAS (layer 2 in place): each wave reads
// its 16 rows before any store (stores depend on MFMAs depend on loads).
template <bool RELU>
__global__ __launch_bounds__(256) void k_dual_gemm_mfma(
    const float* h,
    const float* __restrict__ Wn,
    const float* __restrict__ Wi,
    const float* __restrict__ bias,
    const float* __restrict__ dinv,
    __hip_bfloat16* __restrict__ t, float* agg, int N) {
  __shared__ short Wn_f[4096];   // 8 frags x 64 lanes x 8 bf16
  __shared__ short Wi_f[4096];
  __shared__ float b_s[64];

  const int tid = threadIdx.x;
  for (int i = tid; i < 4096; i += 256) {
    int k = i >> 6, n = i & 63;
    // frag coords: kb=k>>5, quad=(k>>3)&3, j=k&7, ct=n>>4, m=n&15
    int dst = (((n >> 4) * 2 + (k >> 5)) * 64 + ((k >> 3) & 3) * 16 + (n & 15)) * 8 + (k & 7);
    __hip_bfloat16 a = __float2bfloat16(Wn[i]);
    __hip_bfloat16 b = __float2bfloat16(Wi[i]);
    Wn_f[dst] = *(short*)&a;
    Wi_f[dst] = *(short*)&b;
  }
  if (tid < 64) b_s[tid] = bias[tid];
  __syncthreads();

  const int lane = tid & 63;
  const int w = tid >> 6;
  const int m = lane & 15;
  const int quad = lane >> 4;

  // B fragments: one ds_read_b128 each
  bfrag Bn[4][2], Bi[4][2];
#pragma unroll
  for (int ct = 0; ct < 4; ++ct)
#pragma unroll
    for (int kb = 0; kb < 2; ++kb) {
      Bn[ct][kb] = *(const bfrag*)&Wn_f[((ct * 2 + kb) * 64 + lane) * 8];
      Bi[ct][kb] = *(const bfrag*)&Wi_f[((ct * 2 + kb) * 64 + lane) * 8];
    }

  const int r0 = blockIdx.x * 64 + w * 16;   // this wave's 16-row tile
  const int arow = r0 + m;

  // A fragments: A[m][k = kb*32 + quad*8 + j] from fp32 h (relu fused)
  bfrag A[2];
#pragma unroll
  for (int kb = 0; kb < 2; ++kb) {
    bfrag av = {};
    if (arow < N) {
      const float* src = &h[(size_t)arow * 64 + kb * 32 + quad * 8];
      float4 f0 = *(const float4*)src;
      float4 f1 = *(const float4*)(src + 4);
      float tmp[8] = {f0.x, f0.y, f0.z, f0.w, f1.x, f1.y, f1.z, f1.w};
#pragma unroll
      for (int j = 0; j < 8; ++j) {
        float v = RELU ? fmaxf(tmp[j], 0.f) : tmp[j];
        __hip_bfloat16 hb = __float2bfloat16(v);
        av[j] = *(short*)&hb;
      }
    }
    A[kb] = av;
  }

  f32x4 accT[4], accA[4];
#pragma unroll
  for (int ct = 0; ct < 4; ++ct) {
    f32x4 z = {0.f, 0.f, 0.f, 0.f};
    accT[ct] = z;
    accA[ct] = z;
  }
#pragma unroll
  for (int ct = 0; ct < 4; ++ct) {
    accT[ct] = __builtin_amdgcn_mfma_f32_16x16x32_bf16(A[0], Bn[ct][0], accT[ct], 0, 0, 0);
    accT[ct] = __builtin_amdgcn_mfma_f32_16x16x32_bf16(A[1], Bn[ct][1], accT[ct], 0, 0, 0);
    accA[ct] = __builtin_amdgcn_mfma_f32_16x16x32_bf16(A[0], Bi[ct][0], accA[ct], 0, 0, 0);
    accA[ct] = __builtin_amdgcn_mfma_f32_16x16x32_bf16(A[1], Bi[ct][1], accA[ct], 0, 0, 0);
  }

  // epilogue: C/D row = quad*4 + reg, col = ct*16 + m
#pragma unroll
  for (int reg = 0; reg < 4; ++reg) {
    int r = r0 + quad * 4 + reg;
    if (r < N) {
      float dv = dinv[r];
#pragma unroll
      for (int ct = 0; ct < 4; ++ct) {
        int col = ct * 16 + m;
        t[(size_t)r * 64 + col] = __float2bfloat16(accT[ct][reg] * dv);
        agg[(size_t)r * 64 + col] = accA[ct][reg] + b_s[col];
      }
    }
  }
}

// ---------- CSR gather (layer 1): agg[n] += dinv[n] * sum_e t'[row_e] ----------
__global__ __launch_bounds__(256) void k_gather(
    const int* __restrict__ csr_row, const int* __restrict__ ptr,
    const int* __restrict__ indeg, const float* __restrict__ dinv,
    const __hip_bfloat16* __restrict__ t, float* __restrict__ agg, int N) {
  int n = blockIdx.x * 4 + (threadIdx.x >> 6);
  if (n >= N) return;
  int lane = threadIdx.x & 63;
  int q = lane >> 4;
  int fl = lane & 15;
  int i0 = ptr[n];
  int end = i0 + indeg[n];
  float dn = dinv[n];

  float4 aggv = make_float4(0.f, 0.f, 0.f, 0.f);
  if (q == 0) aggv = *(const float4*)&agg[(size_t)n * 64 + 4 * fl];

  float4 acc = make_float4(0.f, 0.f, 0.f, 0.f);
  int i = i0 + q;
  for (; i + 4 < end; i += 8) {
    int ra = csr_row[i];
    int rb = csr_row[i + 4];
    ushort4 ua = *(const ushort4*)&t[(size_t)ra * 64 + 4 * fl];
    ushort4 ub = *(const ushort4*)&t[(size_t)rb * 64 + 4 * fl];
    float4 va, vb;
    ((unsigned*)&va)[0] = (unsigned)ua.x << 16; ((unsigned*)&va)[1] = (unsigned)ua.y << 16;
    ((unsigned*)&va)[2] = (unsigned)ua.z << 16; ((unsigned*)&va)[3] = (unsigned)ua.w << 16;
    ((unsigned*)&vb)[0] = (unsigned)ub.x << 16; ((unsigned*)&vb)[1] = (unsigned)ub.y << 16;
    ((unsigned*)&vb)[2] = (unsigned)ub.z << 16; ((unsigned*)&vb)[3] = (unsigned)ub.w << 16;
    acc.x += va.x + vb.x; acc.y += va.y + vb.y;
    acc.z += va.z + vb.z; acc.w += va.w + vb.w;
  }
  for (; i < end; i += 4) {
    int ra = csr_row[i];
    ushort4 ua = *(const ushort4*)&t[(size_t)ra * 64 + 4 * fl];
    float4 va;
    ((unsigned*)&va)[0] = (unsigned)ua.x << 16; ((unsigned*)&va)[1] = (unsigned)ua.y << 16;
    ((unsigned*)&va)[2] = (unsigned)ua.z << 16; ((unsigned*)&va)[3] = (unsigned)ua.w << 16;
    acc.x += va.x; acc.y += va.y; acc.z += va.z; acc.w += va.w;
  }
  acc.x += __shfl_xor(acc.x, 16); acc.y += __shfl_xor(acc.y, 16);
  acc.z += __shfl_xor(acc.z, 16); acc.w += __shfl_xor(acc.w, 16);
  acc.x += __shfl_xor(acc.x, 32); acc.y += __shfl_xor(acc.y, 32);
  acc.z += __shfl_xor(acc.z, 32); acc.w += __shfl_xor(acc.w, 32);
  if (q == 0) {
    aggv.x += dn * acc.x; aggv.y += dn * acc.y;
    aggv.z += dn * acc.z; aggv.w += dn * acc.w;
    *(float4*)&agg[(size_t)n * 64 + 4 * fl] = aggv;
  }
}

// ---------- FUSED layer-2 gather + output GEMM (round-10 proven structure) ----------
__global__ __launch_bounds__(256) void k_gather_out(
    const int* __restrict__ csr_row, const int* __restrict__ ptr,
    const int* __restrict__ indeg, const float* __restrict__ dinv,
    const __hip_bfloat16* __restrict__ t, const float* __restrict__ agg,
    const float* __restrict__ Wo,   // [64,32]
    const float* __restrict__ bo,   // [32]
    float* __restrict__ out, int N) {
  __shared__ float Wo_s[64 * 32];
  __shared__ float bo_s[32];
  __shared__ float rowbuf[4][64];

  const int tid = threadIdx.x;
  for (int i = tid; i < 2048; i += 256) Wo_s[i] = Wo[i];
  if (tid < 32) bo_s[tid] = bo[tid];
  __syncthreads();   // barrier BEFORE any divergent exit

  int w = tid >> 6;                 // wave id 0..3
  int n = blockIdx.x * 4 + w;
  if (n >= N) return;
  int lane = tid & 63;
  int q = lane >> 4;
  int fl = lane & 15;
  int i0 = ptr[n];
  int end = i0 + indeg[n];
  float dn = dinv[n];

  float4 aggv = make_float4(0.f, 0.f, 0.f, 0.f);
  if (q == 0) aggv = *(const float4*)&agg[(size_t)n * 64 + 4 * fl];

  float4 acc = make_float4(0.f, 0.f, 0.f, 0.f);
  int i = i0 + q;
  for (; i + 4 < end; i += 8) {
    int ra = csr_row[i];
    int rb = csr_row[i + 4];
    ushort4 ua = *(const ushort4*)&t[(size_t)ra * 64 + 4 * fl];
    ushort4 ub = *(const ushort4*)&t[(size_t)rb * 64 + 4 * fl];
    float4 va, vb;
    ((unsigned*)&va)[0] = (unsigned)ua.x << 16; ((unsigned*)&va)[1] = (unsigned)ua.y << 16;
    ((unsigned*)&va)[2] = (unsigned)ua.z << 16; ((unsigned*)&va)[3] = (unsigned)ua.w << 16;
    ((unsigned*)&vb)[0] = (unsigned)ub.x << 16; ((unsigned*)&vb)[1] = (unsigned)ub.y << 16;
    ((unsigned*)&vb)[2] = (unsigned)ub.z << 16; ((unsigned*)&vb)[3] = (unsigned)ub.w << 16;
    acc.x += va.x + vb.x; acc.y += va.y + vb.y;
    acc.z += va.z + vb.z; acc.w += va.w + vb.w;
  }
  for (; i < end; i += 4) {
    int ra = csr_row[i];
    ushort4 ua = *(const ushort4*)&t[(size_t)ra * 64 + 4 * fl];
    float4 va;
    ((unsigned*)&va)[0] = (unsigned)ua.x << 16; ((unsigned*)&va)[1] = (unsigned)ua.y << 16;
    ((unsigned*)&va)[2] = (unsigned)ua.z << 16; ((unsigned*)&va)[3] = (unsigned)ua.w << 16;
    acc.x += va.x; acc.y += va.y; acc.z += va.z; acc.w += va.w;
  }
  acc.x += __shfl_xor(acc.x, 16); acc.y += __shfl_xor(acc.y, 16);
  acc.z += __shfl_xor(acc.z, 16); acc.w += __shfl_xor(acc.w, 16);
  acc.x += __shfl_xor(acc.x, 32); acc.y += __shfl_xor(acc.y, 32);
  acc.z += __shfl_xor(acc.z, 32); acc.w += __shfl_xor(acc.w, 32);
  if (q == 0) {
    rowbuf[w][4 * fl + 0] = fmaxf(aggv.x + dn * acc.x, 0.f);
    rowbuf[w][4 * fl + 1] = fmaxf(aggv.y + dn * acc.y, 0.f);
    rowbuf[w][4 * fl + 2] = fmaxf(aggv.z + dn * acc.z, 0.f);
    rowbuf[w][4 * fl + 3] = fmaxf(aggv.w + dn * acc.w, 0.f);
  }
  // same-wave LDS RAW: compiler inserts lgkmcnt wait; no barrier needed.
  int half = lane >> 5;      // k-range half
  int j = lane & 31;         // output column
  float ov = 0.f;
#pragma unroll 8
  for (int k = 32 * half; k < 32 * half + 32; ++k)
    ov = fmaf(rowbuf[w][k], Wo_s[k * 32 + j], ov);
  ov += __shfl_xor(ov, 32);
  if (half == 0) out[(size_t)n * 32 + j] = ov + bo_s[j];
}

extern "C" void kernel_launch(void* const* d_in, const int* in_sizes, int n_in,
                              void* d_out, int out_size, void* d_ws, size_t ws_size,
                              hipStream_t stream) {
  const float* x = (const float*)d_in[0];
  const int* ei = (const int*)d_in[1];
  const float* W_in1 = (const float*)d_in[2];
  const float* W_neigh1 = (const float*)d_in[3];
  const float* bias1 = (const float*)d_in[4];
  const float* W_in2 = (const float*)d_in[5];
  const float* W_neigh2 = (const float*)d_in[6];
  const float* bias2 = (const float*)d_in[7];
  const float* W_out = (const float*)d_in[8];
  const float* b_out = (const float*)d_in[9];
  float* out = (float*)d_out;

  const int N = in_sizes[0] / 64;
  const int E = in_sizes[1] / 2;

  char* ws = (char*)d_ws;
  size_t off = 0;
  auto alloc = [&](size_t bytes) -> void* {
    void* p = ws + off;
    off += (bytes + 255) & ~(size_t)255;
    return p;
  };
  float* dinv = (float*)alloc((size_t)N * 4);
  int* indeg = (int*)alloc((size_t)N * 4);
  int* ptr = (int*)alloc((size_t)N * 4);
  int* bsum = (int*)alloc(256);
  int* csr_row = (int*)alloc((size_t)E * 4);
  int* partial = (int*)alloc((size_t)2 * NCHUNK * N * 4);
  int* base = (int*)alloc((size_t)NCHUNK * N * 4);
  __hip_bfloat16* t = (__hip_bfloat16*)alloc((size_t)N * 64 * 2);
  float* agg = (float*)alloc((size_t)N * 64 * 4);
  (void)ws_size;

  int range_h = (N + NRANGE_H - 1) / NRANGE_H;  // 12500 <= HIST_H
  int range_b = (N + NRANGE_B - 1) / NRANGE_B;  // 12500 <= HIST_B2
  int gN = (N + 255) / 256;
  int gRows = (N + 63) / 64;
  int gNode = (N + 3) / 4;
  int nb = (N + 1023) / 1024;

  k_hist<<<2 * NRANGE_H * NCHUNK, 1024, 0, stream>>>(ei, partial, N, E, range_h);
  k_dinv_scan<<<nb, 1024, 0, stream>>>(partial, dinv, indeg, ptr, bsum, N);
  k_base<<<gN, 256, 0, stream>>>(partial, bsum, ptr, base, N, nb);
  k_bin2<<<NRANGE_B * NCHUNK, 1024, 0, stream>>>(ei, base, csr_row, N, E, range_b);

  // layer 1 (MFMA)
  k_dual_gemm_mfma<false><<<gRows, 256, 0, stream>>>(x, W_neigh1, W_in1, bias1, dinv, t, agg, N);
  k_gather<<<gNode, 256, 0, stream>>>(csr_row, ptr, indeg, dinv, t, agg, N);

  // layer 2 (MFMA, in-place on agg), then fused gather+output
  k_dual_gemm_mfma<true><<<gRows, 256, 0, stream>>>(agg, W_neigh2, W_in2, bias2, dinv, t, agg, N);
  k_gather_out<<<gNode, 256, 0, stream>>>(csr_row, ptr, indeg, dinv, t, agg,
                                          W_out, b_out, out, N);
}

// Round 16
// 198.560 us; speedup vs baseline: 1.3479x; 1.0231x over previous
//
#include <hip/hip_runtime.h>
#include <hip/hip_bf16.h>

// Pipeline (no global atomics — write through to HBM per-op; rounds 3/4).
// Build needs >=256 blocks / >=100K threads (rounds 5/7). Gathers are at the
// compulsory-miss x random-BW floor (~41MB FETCH, ~44us; r11-r13). Round 16:
// layer-1 GEMM made build-independent (no dinv prescale on t1; gather-1 uses
// per-edge dinv[ra] — r10-measured identical) and FUSED into the k_hist
// dispatch via a block-range branch (hist blocks + gemm blocks overlap
// across CUs). 8 -> 7 dispatches. Layer-2 keeps prescale; gather_out pure-add.

#define NCHUNK 32     // edge chunks
#define NRANGE_H 4    // hist node ranges (range = 12500)
#define HIST_H 12544
#define NRANGE_B 4    // bin2 node ranges (range = 12500)
#define HIST_B2 12544

typedef __attribute__((ext_vector_type(8))) short bfrag;   // 8 bf16 = 4 VGPRs
typedef __attribute__((ext_vector_type(4))) float f32x4;

// ---------- MFMA 16-row wave tile: t = h@Wn (opt *dinv), agg = h@Wi + bias ----------
// W LDS layout is FRAGMENT ORDER: frag (ct,kb) at shorts [((ct*2+kb)*64+lane)*8].
template <bool RELU, bool PRESCALE>
__device__ __forceinline__ void gemm_tile16(
    const float* h, const float* __restrict__ dinv,
    const short* Wn_f, const short* Wi_f, const float* b_s,
    __hip_bfloat16* __restrict__ t, float* agg, int r0, int lane, int N) {
  const int m = lane & 15;
  const int quad = lane >> 4;

  bfrag Bn[4][2], Bi[4][2];
#pragma unroll
  for (int ct = 0; ct < 4; ++ct)
#pragma unroll
    for (int kb = 0; kb < 2; ++kb) {
      Bn[ct][kb] = *(const bfrag*)&Wn_f[((ct * 2 + kb) * 64 + lane) * 8];
      Bi[ct][kb] = *(const bfrag*)&Wi_f[((ct * 2 + kb) * 64 + lane) * 8];
    }

  const int arow = r0 + m;
  bfrag A[2];
#pragma unroll
  for (int kb = 0; kb < 2; ++kb) {
    bfrag av = {};
    if (arow < N) {
      const float* src = &h[(size_t)arow * 64 + kb * 32 + quad * 8];
      float4 f0 = *(const float4*)src;
      float4 f1 = *(const float4*)(src + 4);
      float tmp[8] = {f0.x, f0.y, f0.z, f0.w, f1.x, f1.y, f1.z, f1.w};
#pragma unroll
      for (int j = 0; j < 8; ++j) {
        float v = RELU ? fmaxf(tmp[j], 0.f) : tmp[j];
        __hip_bfloat16 hb = __float2bfloat16(v);
        av[j] = *(short*)&hb;
      }
    }
    A[kb] = av;
  }

  f32x4 accT[4], accA[4];
#pragma unroll
  for (int ct = 0; ct < 4; ++ct) {
    f32x4 z = {0.f, 0.f, 0.f, 0.f};
    accT[ct] = z;
    accA[ct] = z;
  }
#pragma unroll
  for (int ct = 0; ct < 4; ++ct) {
    accT[ct] = __builtin_amdgcn_mfma_f32_16x16x32_bf16(A[0], Bn[ct][0], accT[ct], 0, 0, 0);
    accT[ct] = __builtin_amdgcn_mfma_f32_16x16x32_bf16(A[1], Bn[ct][1], accT[ct], 0, 0, 0);
    accA[ct] = __builtin_amdgcn_mfma_f32_16x16x32_bf16(A[0], Bi[ct][0], accA[ct], 0, 0, 0);
    accA[ct] = __builtin_amdgcn_mfma_f32_16x16x32_bf16(A[1], Bi[ct][1], accA[ct], 0, 0, 0);
  }

#pragma unroll
  for (int reg = 0; reg < 4; ++reg) {
    int r = r0 + quad * 4 + reg;
    if (r < N) {
      float dv = PRESCALE ? dinv[r] : 1.0f;
#pragma unroll
      for (int ct = 0; ct < 4; ++ct) {
        int col = ct * 16 + m;
        float tv = PRESCALE ? accT[ct][reg] * dv : accT[ct][reg];
        t[(size_t)r * 64 + col] = __float2bfloat16(tv);
        agg[(size_t)r * 64 + col] = accA[ct][reg] + b_s[col];
      }
    }
  }
}

// W staging in fragment order (256 or 1024 threads)
__device__ __forceinline__ void stage_W_frag(const float* __restrict__ Wn,
                                             const float* __restrict__ Wi,
                                             short* Wn_f, short* Wi_f,
                                             int tid, int nthr) {
  for (int i = tid; i < 4096; i += nthr) {
    int k = i >> 6, n = i & 63;
    int dst = (((n >> 4) * 2 + (k >> 5)) * 64 + ((k >> 3) & 3) * 16 + (n & 15)) * 8 + (k & 7);
    __hip_bfloat16 a = __float2bfloat16(Wn[i]);
    __hip_bfloat16 b = __float2bfloat16(Wi[i]);
    Wn_f[dst] = *(short*)&a;
    Wi_f[dst] = *(short*)&b;
  }
}

// ---------- FUSED dispatch 1: layer-1 GEMM blocks + histogram blocks ----------
// blocks [0, gemmBlocks): GEMM (256 rows/block, 16 waves x 16-row tiles)
// blocks [gemmBlocks, +2*NRANGE_H*NCHUNK): partial histograms
__global__ __launch_bounds__(1024) void k_hist_gemm1(
    const int* __restrict__ ei, int* __restrict__ partial,
    const float* __restrict__ x,
    const float* __restrict__ Wn, const float* __restrict__ Wi,
    const float* __restrict__ bias,
    __hip_bfloat16* __restrict__ t, float* __restrict__ agg,
    int N, int E, int range, int gemmBlocks) {
  __shared__ __align__(16) char smem[HIST_H * 4];   // union: hist | W frags
  const int tid = threadIdx.x;

  if ((int)blockIdx.x < gemmBlocks) {
    short* Wn_f = (short*)smem;                     // 8192 B
    short* Wi_f = (short*)(smem + 8192);            // 8192 B
    float* b_s = (float*)(smem + 16384);            // 256 B
    stage_W_frag(Wn, Wi, Wn_f, Wi_f, tid, 1024);
    if (tid < 64) b_s[tid] = bias[tid];
    __syncthreads();
    int w = tid >> 6;
    int lane = tid & 63;
    int r0 = blockIdx.x * 256 + w * 16;
    gemm_tile16<false, false>(x, nullptr, Wn_f, Wi_f, b_s, t, agg, r0, lane, N);
    return;
  }

  int* hist = (int*)smem;
  int bid = blockIdx.x - gemmBlocks;
  int c = bid % NCHUNK;
  int r = (bid / NCHUNK) % NRANGE_H;
  int a = bid / (NCHUNK * NRANGE_H);
  const int* ids = ei + (size_t)a * E;
  int lo = r * range;
  int hi = min(N, lo + range);
  int len = hi - lo;
  for (int i = tid; i < len; i += 1024) hist[i] = 0;
  __syncthreads();
  int e0 = (int)((long long)E * c / NCHUNK);
  int e1 = (int)((long long)E * (c + 1) / NCHUNK);
  for (int e = e0 + tid; e < e1; e += 1024) {
    int id = ids[e];
    if (id >= lo && id < hi) atomicAdd(&hist[id - lo], 1);  // LDS atomic
  }
  __syncthreads();
  int* dst = partial + ((size_t)a * NCHUNK + c) * N + lo;
  for (int i = tid; i < len; i += 1024) dst[i] = hist[i];
}

// ---------- fused: reduce partials -> dinv/indeg, then in-block exscan ----------
__global__ __launch_bounds__(1024) void k_dinv_scan(const int* __restrict__ partial,
                                                    float* __restrict__ dinv,
                                                    int* __restrict__ indeg,
                                                    int* __restrict__ ptr,
                                                    int* __restrict__ bsum, int N) {
  __shared__ int s[1024];
  int g = blockIdx.x * 1024 + threadIdx.x;
  int deg = 0, ind = 0;
  if (g < N) {
#pragma unroll
    for (int c = 0; c < NCHUNK; ++c) {
      deg += partial[(size_t)c * N + g];
      ind += partial[((size_t)NCHUNK + c) * N + g];
    }
    dinv[g] = (deg > 0) ? (1.0f / sqrtf((float)deg)) : 0.0f;
    indeg[g] = ind;
  }
  s[threadIdx.x] = ind;
  __syncthreads();
  for (int off = 1; off < 1024; off <<= 1) {
    int tv = (threadIdx.x >= off) ? s[threadIdx.x - off] : 0;
    __syncthreads();
    s[threadIdx.x] += tv;
    __syncthreads();
  }
  if (g < N) ptr[g] = s[threadIdx.x] - ind;  // exclusive within block
  if (threadIdx.x == 1023) bsum[blockIdx.x] = s[1023];
}

// ---------- fused: scan bsum (in LDS) + finalize ptr + emit bases ----------
__global__ __launch_bounds__(256) void k_base(const int* __restrict__ partial,
                                              const int* __restrict__ bsum,
                                              int* __restrict__ ptr,
                                              int* __restrict__ base, int N, int nb) {
  __shared__ int pbs[64];
  if (threadIdx.x == 0) {
    int acc = 0;
    for (int i = 0; i < nb; ++i) { pbs[i] = acc; acc += bsum[i]; }
  }
  __syncthreads();
  int n = blockIdx.x * 256 + threadIdx.x;
  if (n >= N) return;
  int run = ptr[n] + pbs[n >> 10];
  ptr[n] = run;                      // final global exclusive scan
#pragma unroll
  for (int c = 0; c < NCHUNK; ++c) {
    base[(size_t)c * N + n] = run;
    run += partial[((size_t)NCHUNK + c) * N + n];
  }
}

// ---------- counting-sort binning (LDS atomics on cnt; base from L2) ----------
__global__ __launch_bounds__(1024) void k_bin2(const int* __restrict__ ei,
                                               const int* __restrict__ base,
                                               int* __restrict__ csr_row,
                                               int N, int E, int range) {
  __shared__ int cnt[HIST_B2];   // 50 KB
  int c = blockIdx.x % NCHUNK;
  int r = blockIdx.x / NCHUNK;
  const int* row = ei;
  const int* col = ei + E;
  int lo = r * range;
  int hi = min(N, lo + range);
  int len = hi - lo;
  for (int i = threadIdx.x; i < len; i += 1024) cnt[i] = 0;
  __syncthreads();
  int e0 = (int)((long long)E * c / NCHUNK);
  int e1 = (int)((long long)E * (c + 1) / NCHUNK);
  const int* bslice = base + (size_t)c * N;
  for (int e = e0 + threadIdx.x; e < e1; e += 1024) {
    int cl = col[e];
    int rw = row[e];
    if (cl >= lo && cl < hi) {
      int off = atomicAdd(&cnt[cl - lo], 1);   // LDS atomic
      csr_row[bslice[cl] + off] = rw;          // base in L2; plain store
    }
  }
}

// ---------- standalone layer-2 MFMA dual GEMM (prescaled t2, relu on load) ----------
__global__ __launch_bounds__(256) void k_dual_gemm2(
    const float* h,            // aliases agg (in place)
    const float* __restrict__ Wn,
    const float* __restrict__ Wi,
    const float* __restrict__ bias,
    const float* __restrict__ dinv,
    __hip_bfloat16* __restrict__ t, float* agg, int N) {
  __shared__ short Wn_f[4096];
  __shared__ short Wi_f[4096];
  __shared__ float b_s[64];
  const int tid = threadIdx.x;
  stage_W_frag(Wn, Wi, Wn_f, Wi_f, tid, 256);
  if (tid < 64) b_s[tid] = bias[tid];
  __syncthreads();
  int w = tid >> 6;
  int lane = tid & 63;
  int r0 = blockIdx.x * 64 + w * 16;
  gemm_tile16<true, true>(h, dinv, Wn_f, Wi_f, b_s, t, agg, r0, lane, N);
}

// ---------- CSR gather (layer 1, r10 form): agg[n] += t[ra]*dinv[ra]*dinv[n] ----------
__global__ __launch_bounds__(256) void k_gather(
    const int* __restrict__ csr_row, const int* __restrict__ ptr,
    const int* __restrict__ indeg, const float* __restrict__ dinv,
    const __hip_bfloat16* __restrict__ t, float* __restrict__ agg, int N) {
  int n = blockIdx.x * 4 + (threadIdx.x >> 6);
  if (n >= N) return;
  int lane = threadIdx.x & 63;
  int q = lane >> 4;
  int fl = lane & 15;
  int i0 = ptr[n];
  int end = i0 + indeg[n];
  float dn = dinv[n];

  float4 aggv = make_float4(0.f, 0.f, 0.f, 0.f);
  if (q == 0) aggv = *(const float4*)&agg[(size_t)n * 64 + 4 * fl];

  float4 acc = make_float4(0.f, 0.f, 0.f, 0.f);
  int i = i0 + q;
  for (; i + 4 < end; i += 8) {
    int ra = csr_row[i];
    int rb = csr_row[i + 4];
    float na = dinv[ra];
    float nb = dinv[rb];
    ushort4 ua = *(const ushort4*)&t[(size_t)ra * 64 + 4 * fl];
    ushort4 ub = *(const ushort4*)&t[(size_t)rb * 64 + 4 * fl];
    float4 va, vb;
    ((unsigned*)&va)[0] = (unsigned)ua.x << 16; ((unsigned*)&va)[1] = (unsigned)ua.y << 16;
    ((unsigned*)&va)[2] = (unsigned)ua.z << 16; ((unsigned*)&va)[3] = (unsigned)ua.w << 16;
    ((unsigned*)&vb)[0] = (unsigned)ub.x << 16; ((unsigned*)&vb)[1] = (unsigned)ub.y << 16;
    ((unsigned*)&vb)[2] = (unsigned)ub.z << 16; ((unsigned*)&vb)[3] = (unsigned)ub.w << 16;
    acc.x = fmaf(va.x, na, acc.x); acc.y = fmaf(va.y, na, acc.y);
    acc.z = fmaf(va.z, na, acc.z); acc.w = fmaf(va.w, na, acc.w);
    acc.x = fmaf(vb.x, nb, acc.x); acc.y = fmaf(vb.y, nb, acc.y);
    acc.z = fmaf(vb.z, nb, acc.z); acc.w = fmaf(vb.w, nb, acc.w);
  }
  for (; i < end; i += 4) {
    int ra = csr_row[i];
    float na = dinv[ra];
    ushort4 ua = *(const ushort4*)&t[(size_t)ra * 64 + 4 * fl];
    float4 va;
    ((unsigned*)&va)[0] = (unsigned)ua.x << 16; ((unsigned*)&va)[1] = (unsigned)ua.y << 16;
    ((unsigned*)&va)[2] = (unsigned)ua.z << 16; ((unsigned*)&va)[3] = (unsigned)ua.w << 16;
    acc.x = fmaf(va.x, na, acc.x); acc.y = fmaf(va.y, na, acc.y);
    acc.z = fmaf(va.z, na, acc.z); acc.w = fmaf(va.w, na, acc.w);
  }
  acc.x += __shfl_xor(acc.x, 16); acc.y += __shfl_xor(acc.y, 16);
  acc.z += __shfl_xor(acc.z, 16); acc.w += __shfl_xor(acc.w, 16);
  acc.x += __shfl_xor(acc.x, 32); acc.y += __shfl_xor(acc.y, 32);
  acc.z += __shfl_xor(acc.z, 32); acc.w += __shfl_xor(acc.w, 32);
  if (q == 0) {
    aggv.x += dn * acc.x; aggv.y += dn * acc.y;
    aggv.z += dn * acc.z; aggv.w += dn * acc.w;
    *(float4*)&agg[(size_t)n * 64 + 4 * fl] = aggv;
  }
}

// ---------- FUSED layer-2 gather + output GEMM (t2 prescaled: pure-add) ----------
__global__ __launch_bounds__(256) void k_gather_out(
    const int* __restrict__ csr_row, const int* __restrict__ ptr,
    const int* __restrict__ indeg, const float* __restrict__ dinv,
    const __hip_bfloat16* __restrict__ t, const float* __restrict__ agg,
    const float* __restrict__ Wo,   // [64,32]
    const float* __restrict__ bo,   // [32]
    float* __restrict__ out, int N) {
  __shared__ float Wo_s[64 * 32];
  __shared__ float bo_s[32];
  __shared__ float rowbuf[4][64];

  const int tid = threadIdx.x;
  for (int i = tid; i < 2048; i += 256) Wo_s[i] = Wo[i];
  if (tid < 32) bo_s[tid] = bo[tid];
  __syncthreads();   // barrier BEFORE any divergent exit

  int w = tid >> 6;
  int n = blockIdx.x * 4 + w;
  if (n >= N) return;
  int lane = tid & 63;
  int q = lane >> 4;
  int fl = lane & 15;
  int i0 = ptr[n];
  int end = i0 + indeg[n];
  float dn = dinv[n];

  float4 aggv = make_float4(0.f, 0.f, 0.f, 0.f);
  if (q == 0) aggv = *(const float4*)&agg[(size_t)n * 64 + 4 * fl];

  float4 acc = make_float4(0.f, 0.f, 0.f, 0.f);
  int i = i0 + q;
  for (; i + 4 < end; i += 8) {
    int ra = csr_row[i];
    int rb = csr_row[i + 4];
    ushort4 ua = *(const ushort4*)&t[(size_t)ra * 64 + 4 * fl];
    ushort4 ub = *(const ushort4*)&t[(size_t)rb * 64 + 4 * fl];
    float4 va, vb;
    ((unsigned*)&va)[0] = (unsigned)ua.x << 16; ((unsigned*)&va)[1] = (unsigned)ua.y << 16;
    ((unsigned*)&va)[2] = (unsigned)ua.z << 16; ((unsigned*)&va)[3] = (unsigned)ua.w << 16;
    ((unsigned*)&vb)[0] = (unsigned)ub.x << 16; ((unsigned*)&vb)[1] = (unsigned)ub.y << 16;
    ((unsigned*)&vb)[2] = (unsigned)ub.z << 16; ((unsigned*)&vb)[3] = (unsigned)ub.w << 16;
    acc.x += va.x + vb.x; acc.y += va.y + vb.y;
    acc.z += va.z + vb.z; acc.w += va.w + vb.w;
  }
  for (; i < end; i += 4) {
    int ra = csr_row[i];
    ushort4 ua = *(const ushort4*)&t[(size_t)ra * 64 + 4 * fl];
    float4 va;
    ((unsigned*)&va)[0] = (unsigned)ua.x << 16; ((unsigned*)&va)[1] = (unsigned)ua.y << 16;
    ((unsigned*)&va)[2] = (unsigned)ua.z << 16; ((unsigned*)&va)[3] = (unsigned)ua.w << 16;
    acc.x += va.x; acc.y += va.y; acc.z += va.z; acc.w += va.w;
  }
  acc.x += __shfl_xor(acc.x, 16); acc.y += __shfl_xor(acc.y, 16);
  acc.z += __shfl_xor(acc.z, 16); acc.w += __shfl_xor(acc.w, 16);
  acc.x += __shfl_xor(acc.x, 32); acc.y += __shfl_xor(acc.y, 32);
  acc.z += __shfl_xor(acc.z, 32); acc.w += __shfl_xor(acc.w, 32);
  if (q == 0) {
    rowbuf[w][4 * fl + 0] = fmaxf(aggv.x + dn * acc.x, 0.f);
    rowbuf[w][4 * fl + 1] = fmaxf(aggv.y + dn * acc.y, 0.f);
    rowbuf[w][4 * fl + 2] = fmaxf(aggv.z + dn * acc.z, 0.f);
    rowbuf[w][4 * fl + 3] = fmaxf(aggv.w + dn * acc.w, 0.f);
  }
  // same-wave LDS RAW: compiler inserts lgkmcnt wait; no barrier needed.
  int half = lane >> 5;
  int j = lane & 31;
  float ov = 0.f;
#pragma unroll 8
  for (int k = 32 * half; k < 32 * half + 32; ++k)
    ov = fmaf(rowbuf[w][k], Wo_s[k * 32 + j], ov);
  ov += __shfl_xor(ov, 32);
  if (half == 0) out[(size_t)n * 32 + j] = ov + bo_s[j];
}

extern "C" void kernel_launch(void* const* d_in, const int* in_sizes, int n_in,
                              void* d_out, int out_size, void* d_ws, size_t ws_size,
                              hipStream_t stream) {
  const float* x = (const float*)d_in[0];
  const int* ei = (const int*)d_in[1];
  const float* W_in1 = (const float*)d_in[2];
  const float* W_neigh1 = (const float*)d_in[3];
  const float* bias1 = (const float*)d_in[4];
  const float* W_in2 = (const float*)d_in[5];
  const float* W_neigh2 = (const float*)d_in[6];
  const float* bias2 = (const float*)d_in[7];
  const float* W_out = (const float*)d_in[8];
  const float* b_out = (const float*)d_in[9];
  float* out = (float*)d_out;

  const int N = in_sizes[0] / 64;
  const int E = in_sizes[1] / 2;

  char* ws = (char*)d_ws;
  size_t off = 0;
  auto alloc = [&](size_t bytes) -> void* {
    void* p = ws + off;
    off += (bytes + 255) & ~(size_t)255;
    return p;
  };
  float* dinv = (float*)alloc((size_t)N * 4);
  int* indeg = (int*)alloc((size_t)N * 4);
  int* ptr = (int*)alloc((size_t)N * 4);
  int* bsum = (int*)alloc(256);
  int* csr_row = (int*)alloc((size_t)E * 4);
  int* partial = (int*)alloc((size_t)2 * NCHUNK * N * 4);
  int* base = (int*)alloc((size_t)NCHUNK * N * 4);
  __hip_bfloat16* t = (__hip_bfloat16*)alloc((size_t)N * 64 * 2);
  float* agg = (float*)alloc((size_t)N * 64 * 4);
  (void)ws_size;

  int range_h = (N + NRANGE_H - 1) / NRANGE_H;  // 12500 <= HIST_H
  int range_b = (N + NRANGE_B - 1) / NRANGE_B;  // 12500 <= HIST_B2
  int gN = (N + 255) / 256;
  int gRows = (N + 63) / 64;
  int gNode = (N + 3) / 4;
  int nb = (N + 1023) / 1024;
  int gemmBlocks = (N + 255) / 256;             // 256 rows per 1024-thread block

  // dispatch 1: layer-1 GEMM (independent of build) fused with histograms
  k_hist_gemm1<<<gemmBlocks + 2 * NRANGE_H * NCHUNK, 1024, 0, stream>>>(
      ei, partial, x, W_neigh1, W_in1, bias1, t, agg, N, E, range_h, gemmBlocks);
  k_dinv_scan<<<nb, 1024, 0, stream>>>(partial, dinv, indeg, ptr, bsum, N);
  k_base<<<gN, 256, 0, stream>>>(partial, bsum, ptr, base, N, nb);
  k_bin2<<<NRANGE_B * NCHUNK, 1024, 0, stream>>>(ei, base, csr_row, N, E, range_b);

  // layer-1 gather (per-edge dinv[ra], r10 form)
  k_gather<<<gNode, 256, 0, stream>>>(csr_row, ptr, indeg, dinv, t, agg, N);

  // layer 2 (MFMA, in-place on agg, prescaled t2), then fused gather+output
  k_dual_gemm2<<<gRows, 256, 0, stream>>>(agg, W_neigh2, W_in2, bias2, dinv, t, agg, N);
  k_gather_out<<<gNode, 256, 0, stream>>>(csr_row, ptr, indeg, dinv, t, agg,
                                          W_out, b_out, out, N);
}